// Round 9
// baseline (969.463 us; speedup 1.0000x reference)
//
#include <hip/hip_runtime.h>

typedef unsigned int uint;
typedef unsigned short ushort;

#define D 512
#define GBM 256   // M-tile
#define GBN 256   // N-tile
#define GBK 64    // K-step

typedef __attribute__((ext_vector_type(8))) short bf16x8;
typedef __attribute__((ext_vector_type(4))) float f32x4;

__device__ __forceinline__ ushort f2b(float f) {
  uint u = __builtin_bit_cast(uint, f);
  return (ushort)((u + 0x7FFFu + ((u >> 16) & 1u)) >> 16);  // RNE
}
__device__ __forceinline__ float b_lo(uint u) { return __builtin_bit_cast(float, u << 16); }
__device__ __forceinline__ float b_hi(uint u) { return __builtin_bit_cast(float, u & 0xFFFF0000u); }

__device__ __forceinline__ void gload16(const void* g, void* l) {
  __builtin_amdgcn_global_load_lds((const __attribute__((address_space(1))) void*)g,
                                   (__attribute__((address_space(3))) void*)l, 16, 0, 0);
}

// ---------------- f32 -> bf16 bulk convert (8 elems/thread) ----------------
__global__ __launch_bounds__(256) void f32_to_bf16_vec(const float* __restrict__ in,
                                                       ushort* __restrict__ out, int n8) {
  const int i = blockIdx.x * 256 + threadIdx.x;
  if (i >= n8) return;
  const float4* p = (const float4*)in + (size_t)i * 2;
  float4 a = p[0], b = p[1];
  uint4 o;
  o.x = f2b(a.x) | ((uint)f2b(a.y) << 16);
  o.y = f2b(a.z) | ((uint)f2b(a.w) << 16);
  o.z = f2b(b.x) | ((uint)f2b(b.y) << 16);
  o.w = f2b(b.z) | ((uint)f2b(b.w) << 16);
  ((uint4*)out)[i] = o;
}

// ------------- transpose 512x512 f32 [k][o] -> bf16 BT [o][k] --------------
__global__ __launch_bounds__(256) void transpose_bf16(const float* __restrict__ W,
                                                      ushort* __restrict__ BT) {
  __shared__ float tile[64][65];
  const int bk = blockIdx.x * 64;  // k block
  const int bo = blockIdx.y * 64;  // o block
  const int tx = threadIdx.x & 63, ty = threadIdx.x >> 6;
#pragma unroll
  for (int r = 0; r < 64; r += 4)
    tile[r + ty][tx] = W[(size_t)(bk + r + ty) * D + bo + tx];
  __syncthreads();
#pragma unroll
  for (int r = 0; r < 64; r += 4)
    BT[(size_t)(bo + r + ty) * D + bk + tx] = f2b(tile[tx][r + ty]);
}

// ---------------------------- CSR build ------------------------------------
__global__ void count_deg(const int* __restrict__ dst, int* __restrict__ deg, int E) {
  const int e = blockIdx.x * 256 + threadIdx.x;
  if (e < E) atomicAdd(&deg[dst[e]], 1);
}

__global__ __launch_bounds__(256) void scan_block(const int* __restrict__ in,
                                                  int* __restrict__ out,
                                                  int* __restrict__ bsum) {
  __shared__ int sm[256];
  const int t = threadIdx.x;
  const int gi = blockIdx.x * 256 + t;
  const int v = in[gi];
  int x = v;
  sm[t] = x;
  __syncthreads();
#pragma unroll
  for (int off = 1; off < 256; off <<= 1) {
    const int y = (t >= off) ? sm[t - off] : 0;
    __syncthreads();
    x += y;
    sm[t] = x;
    __syncthreads();
  }
  out[gi] = x - v;  // exclusive
  if (t == 255 && bsum) bsum[blockIdx.x] = x;
}

__global__ void scan_fixup(int* __restrict__ rowptr, const int* __restrict__ bsum,
                           int* __restrict__ cursor, int N, int E) {
  const int i = blockIdx.x * 256 + threadIdx.x;
  const int r = rowptr[i] + bsum[i >> 8];
  rowptr[i] = r;
  cursor[i] = r;
  if (i == 0) rowptr[N] = E;
}

__global__ void fill_csr(const int* __restrict__ src, const int* __restrict__ dst,
                         int* __restrict__ cursor, int* __restrict__ csr, int E) {
  const int e = blockIdx.x * 256 + threadIdx.x;
  if (e >= E) return;
  const int pos = atomicAdd(&cursor[dst[e]], 1);
  csr[pos] = src[e];
}

// ------------------- graph start offsets (batch is sorted) -----------------
__global__ void compute_gstart(const int* __restrict__ batch, int* __restrict__ gstart,
                               int N, int B) {
  const int n = blockIdx.x * 256 + threadIdx.x;
  if (n >= N) return;
  const int b = batch[n];
  const int bp = (n == 0) ? -1 : batch[n - 1];
  for (int x = bp + 1; x <= b; ++x) gstart[x] = n;
  if (n == N - 1)
    for (int x = b + 1; x <= B; ++x) gstart[x] = N;
}

// --------------- GIN aggregation: h = (1+eps)*x + sum_nbr x ----------------
// At its random-gather structural floor (R2/R4/R7 evidence). Do not touch.
#define ACC8(v)                                          \
  a[0] += b_lo((v).x); a[1] += b_hi((v).x);              \
  a[2] += b_lo((v).y); a[3] += b_hi((v).y);              \
  a[4] += b_lo((v).z); a[5] += b_hi((v).z);              \
  a[6] += b_lo((v).w); a[7] += b_hi((v).w)

__global__ __launch_bounds__(256) void agg_kernel(const ushort* __restrict__ xb,
                                                  const int* __restrict__ rowptr,
                                                  const int* __restrict__ csr,
                                                  const float* __restrict__ eps_arr,
                                                  int layer, ushort* __restrict__ h) {
  const int node = blockIdx.x * 4 + (threadIdx.x >> 6);
  const int lane = threadIdx.x & 63;
  const float sc = 1.0f + eps_arr[layer];
  const size_t off = (size_t)lane * 8;
  const size_t base = (size_t)node * D + off;
  const uint4 u = *(const uint4*)(xb + base);
  float a[8];
  a[0] = b_lo(u.x) * sc; a[1] = b_hi(u.x) * sc;
  a[2] = b_lo(u.y) * sc; a[3] = b_hi(u.y) * sc;
  a[4] = b_lo(u.z) * sc; a[5] = b_hi(u.z) * sc;
  a[6] = b_lo(u.w) * sc; a[7] = b_hi(u.w) * sc;
  int e = rowptr[node];
  const int en = rowptr[node + 1];
  for (; e + 4 <= en; e += 4) {
    const int s0 = csr[e], s1 = csr[e + 1], s2 = csr[e + 2], s3 = csr[e + 3];
    const uint4 v0 = *(const uint4*)(xb + (size_t)s0 * D + off);
    const uint4 v1 = *(const uint4*)(xb + (size_t)s1 * D + off);
    const uint4 v2 = *(const uint4*)(xb + (size_t)s2 * D + off);
    const uint4 v3 = *(const uint4*)(xb + (size_t)s3 * D + off);
    ACC8(v0); ACC8(v1); ACC8(v2); ACC8(v3);
  }
  if (e + 2 <= en) {
    const int s0 = csr[e], s1 = csr[e + 1];
    const uint4 v0 = *(const uint4*)(xb + (size_t)s0 * D + off);
    const uint4 v1 = *(const uint4*)(xb + (size_t)s1 * D + off);
    ACC8(v0); ACC8(v1);
    e += 2;
  }
  if (e < en) {
    const uint4 v0 = *(const uint4*)(xb + (size_t)csr[e] * D + off);
    ACC8(v0);
  }
  uint4 o;
  o.x = f2b(a[0]) | ((uint)f2b(a[1]) << 16);
  o.y = f2b(a[2]) | ((uint)f2b(a[3]) << 16);
  o.z = f2b(a[4]) | ((uint)f2b(a[5]) << 16);
  o.w = f2b(a[6]) | ((uint)f2b(a[7]) << 16);
  *(uint4*)(h + base) = o;
}

// --------- bf16 GEMM: O = leaky(A @ BT^T + bias), 256² tile, BK=64 ---------
// T4 upgrade vs R8: raw s_barrier + COUNTED vmcnt(8) instead of __syncthreads
// (which drains vmcnt to 0 every K-iter, exposing the prefetch).
// Per iter t: STAGE(t+1 -> other buf); vmcnt(8) [waits only tile t's 8 loads,
// leaves t+1's in flight]; s_barrier; COMPUTE(buf t); s_barrier [protects the
// buffer before next iter's STAGE overwrites it]. Hazards: WAR by post-compute
// barrier; RAW by vmcnt+barrier; no divergence -> barrier pairing safe.
// Chunk-XOR swizzle (rule 21, both sides) as verified in R5-R8.
__global__ __launch_bounds__(512, 1) void gemm_bias_leaky(
    const ushort* __restrict__ A, const ushort* __restrict__ BT,
    const float* __restrict__ bias, ushort* __restrict__ Obf,
    float* __restrict__ Of32) {
  __shared__ alignas(16) ushort smem[4 * GBM * GBK];  // 128 KB: A0,B0,A1,B1
  ushort* const lA0 = smem;
  ushort* const lB0 = smem + GBM * GBK;
  ushort* const lA1 = smem + 2 * GBM * GBK;
  ushort* const lB1 = smem + 3 * GBM * GBK;

  const int tid = threadIdx.x;
  const int lane = tid & 63;
  const int wave = tid >> 6;
  const int wr = wave >> 2, wc = wave & 3;  // 2x4 waves; 128x64 out each

  // XCD swizzle (nwg = 512, divisible by 8 -> bijective):
  const int lin = blockIdx.y * gridDim.x + blockIdx.x;
  const int nwg = gridDim.x * gridDim.y;
  const int wg = (lin & 7) * (nwg >> 3) + (lin >> 3);
  const int n0 = (wg & 1) * GBN;
  const size_t m0 = (size_t)(wg >> 1) * GBM;

  // staging: issue i covers rows [i*64, i*64+64); thread tid -> linear LDS
  // 16B slot (i*512+tid); row%8 and source chunk invariant across i.
  const int srow0 = tid >> 3;                        // 0..63
  const int schunk = ((tid & 7) ^ (srow0 & 7)) * 8;  // swizzled global chunk

  f32x4 acc[8][4] = {};

  // fragment-read addressing
  const int rsel = lane & 15;
  const int g = lane >> 4;
  const int key = rsel & 7;

#define STAGE(bufA, bufB, kt)                                                     \
  {                                                                               \
    const int k0_ = (kt) * GBK;                                                   \
    _Pragma("unroll") for (int i_ = 0; i_ < 4; ++i_) {                            \
      const int row_ = i_ * 64 + srow0;                                           \
      gload16(A + (m0 + row_) * D + k0_ + schunk, &(bufA)[(i_ * 512 + wave * 64) * 8]); \
      gload16(BT + (size_t)(n0 + row_) * D + k0_ + schunk,                        \
              &(bufB)[(i_ * 512 + wave * 64) * 8]);                               \
    }                                                                             \
  }

#define COMPUTE(bufA, bufB)                                                       \
  {                                                                               \
    __builtin_amdgcn_s_setprio(1);                                                \
    _Pragma("unroll") for (int kk_ = 0; kk_ < 2; ++kk_) {                         \
      const int ch_ = ((kk_ * 4 + g) ^ key) * 8;                                  \
      bf16x8 af_[8], bf_[4];                                                      \
      _Pragma("unroll") for (int j_ = 0; j_ < 4; ++j_)                            \
          bf_[j_] = *(const bf16x8*)&(bufB)[(wc * 64 + j_ * 16 + rsel) * GBK + ch_]; \
      _Pragma("unroll") for (int i_ = 0; i_ < 8; ++i_)                            \
          af_[i_] = *(const bf16x8*)&(bufA)[(wr * 128 + i_ * 16 + rsel) * GBK + ch_]; \
      _Pragma("unroll") for (int i_ = 0; i_ < 8; ++i_)                            \
          _Pragma("unroll") for (int j_ = 0; j_ < 4; ++j_)                        \
              acc[i_][j_] = __builtin_amdgcn_mfma_f32_16x16x32_bf16(              \
                  af_[i_], bf_[j_], acc[i_][j_], 0, 0, 0);                        \
    }                                                                             \
    __builtin_amdgcn_s_setprio(0);                                                \
  }

#define VMW(N)                                              \
  asm volatile("s_waitcnt vmcnt(" #N ")" ::: "memory");     \
  __builtin_amdgcn_sched_barrier(0)
#define BAR() __builtin_amdgcn_s_barrier()

  // prologue + fully unrolled 8 K-tiles (K=512/GBK)
  STAGE(lA0, lB0, 0);
  STAGE(lA1, lB1, 1); VMW(8); BAR(); COMPUTE(lA0, lB0); BAR();  // t=0
  STAGE(lA0, lB0, 2); VMW(8); BAR(); COMPUTE(lA1, lB1); BAR();  // t=1
  STAGE(lA1, lB1, 3); VMW(8); BAR(); COMPUTE(lA0, lB0); BAR();  // t=2
  STAGE(lA0, lB0, 4); VMW(8); BAR(); COMPUTE(lA1, lB1); BAR();  // t=3
  STAGE(lA1, lB1, 5); VMW(8); BAR(); COMPUTE(lA0, lB0); BAR();  // t=4
  STAGE(lA0, lB0, 6); VMW(8); BAR(); COMPUTE(lA1, lB1); BAR();  // t=5
  STAGE(lA1, lB1, 7); VMW(8); BAR(); COMPUTE(lA0, lB0); BAR();  // t=6
  VMW(0); BAR(); COMPUTE(lA1, lB1);                             // t=7
#undef STAGE
#undef COMPUTE
#undef VMW
  __syncthreads();  // full drain before epilogue reuses smem

  // ---- epilogue: bias + leaky into LDS C-tile [256][256] bf16 (128 KB) ----
  // C/D layout: col=lane&15, row=(lane>>4)*4+reg (m89-verified)
#pragma unroll
  for (int j = 0; j < 4; ++j) {
    const int col = wc * 64 + j * 16 + rsel;
    const float bv = bias[n0 + col];
#pragma unroll
    for (int i = 0; i < 8; ++i) {
#pragma unroll
      for (int q = 0; q < 4; ++q) {
        const int row = wr * 128 + i * 16 + g * 4 + q;
        float v = acc[i][j][q] + bv;
        v = (v > 0.f) ? v : 0.01f * v;
        smem[row * GBN + col] = f2b(v);
      }
    }
  }
  __syncthreads();

  // ---- coalesced store: 32 chunks x 16B = 512B contiguous per row ----
#pragma unroll
  for (int it = 0; it < 16; ++it) {
    const int slot = it * 512 + tid;   // 8192 slots
    const int row = slot >> 5;
    const int chunk = slot & 31;
    const uint4 vv = *(const uint4*)&smem[row * GBN + chunk * 8];
    *(uint4*)(Obf + (m0 + row) * D + n0 + chunk * 8) = vv;
    if (Of32) {
      float4 f0, f1;
      f0.x = b_lo(vv.x); f0.y = b_hi(vv.x); f0.z = b_lo(vv.y); f0.w = b_hi(vv.y);
      f1.x = b_lo(vv.z); f1.y = b_hi(vv.z); f1.z = b_lo(vv.w); f1.w = b_hi(vv.w);
      float* op = Of32 + (m0 + row) * D + n0 + chunk * 8;
      *(float4*)op = f0;
      *(float4*)(op + 4) = f1;
    }
  }
}

// ------------------------- segment max (pooling) ---------------------------
__global__ __launch_bounds__(256) void segmax_partial(const ushort* __restrict__ xb,
                                                      const int* __restrict__ gstart,
                                                      float* __restrict__ partial) {
  const int g = blockIdx.x, s = blockIdx.y, t = threadIdx.x;
  const int st = gstart[g], en = gstart[g + 1];
  const long long cnt = en - st;
  const int lo = st + (int)((cnt * s) >> 3);
  const int hi = st + (int)((cnt * (s + 1)) >> 3);
  float m0 = -3.4e38f, m1 = -3.4e38f;
  for (int n = lo; n < hi; ++n) {
    const uint u = *(const uint*)(xb + (size_t)n * D + t * 2);
    m0 = fmaxf(m0, b_lo(u));
    m1 = fmaxf(m1, b_hi(u));
  }
  float* p = partial + (size_t)(g * 8 + s) * D + t * 2;
  p[0] = m0;
  p[1] = m1;
}

__global__ void segmax_combine(const float* __restrict__ partial, float* __restrict__ maxval) {
  const int i = blockIdx.x * 256 + threadIdx.x;  // < B*D
  const int g = i >> 9, d0 = i & (D - 1);
  float m = partial[(size_t)(g * 8) * D + d0];
#pragma unroll
  for (int s = 1; s < 8; ++s) m = fmaxf(m, partial[(size_t)(g * 8 + s) * D + d0]);
  maxval[i] = m;
}

// ---- part = Sum_s mv[s] @ W_s + Sum_s bias_s  (concat-K batched pool) -----
// mv: [4][64][512] f32 (stage 0 = pre-layer segmax, 1..3 = post-layer).
__global__ __launch_bounds__(256) void pool_gemm4(
    const float* __restrict__ mv, const float* __restrict__ proj_w,
    const float* __restrict__ pool_w, const float* __restrict__ proj_b,
    const float* __restrict__ pool_b, float* __restrict__ part) {
  const int g = blockIdx.x;                       // 64
  const int o = blockIdx.y * 256 + threadIdx.x;   // 512
  float acc = proj_b[o] + pool_b[o] + pool_b[D + o] + pool_b[2 * D + o];
#pragma unroll 1
  for (int s = 0; s < 4; ++s) {
    const float* W = (s == 0) ? proj_w : pool_w + (size_t)(s - 1) * D * D;
    const float* m = mv + ((size_t)s * 64 + g) * D;
#pragma unroll 8
    for (int k = 0; k < D; ++k) acc = fmaf(m[k], W[(size_t)k * D + o], acc);
  }
  part[(size_t)g * D + o] = acc;
}

// ---------------------------------------------------------------------------
extern "C" void kernel_launch(void* const* d_in, const int* in_sizes, int n_in,
                              void* d_out, int out_size, void* d_ws, size_t ws_size,
                              hipStream_t stream) {
  const float* x = (const float*)d_in[0];
  const int* ei = (const int*)d_in[1];
  const int* batch = (const int*)d_in[2];
  const float* proj_w = (const float*)d_in[3];
  const float* proj_b = (const float*)d_in[4];
  const float* lin1_w = (const float*)d_in[5];
  const float* lin1_b = (const float*)d_in[6];
  const float* lin2_w = (const float*)d_in[7];
  const float* lin2_b = (const float*)d_in[8];
  const float* eps = (const float*)d_in[9];
  const float* pool_w = (const float*)d_in[10];
  const float* pool_b = (const float*)d_in[11];

  const int N = in_sizes[0] / D;  // 65536
  const int E = in_sizes[1] / 2;  // 524288
  const int B = 64;
  const int* src = ei;
  const int* dst = ei + E;

  float* part = (float*)d_out;         // [64][512]
  float* xout = part + (size_t)B * D;  // [N][512]

  // workspace carve (~210 MB)
  char* w = (char*)d_ws;
  ushort* xb = (ushort*)w;   w += (size_t)N * D * 2;
  ushort* hb = (ushort*)w;   w += (size_t)N * D * 2;
  ushort* tb = (ushort*)w;   w += (size_t)N * D * 2;
  ushort* l1bt = (ushort*)w; w += (size_t)3 * D * D * 2;
  ushort* l2bt = (ushort*)w; w += (size_t)3 * D * D * 2;
  int* rowptr = (int*)w;     w += (size_t)(N + 4) * 4;
  int* cursor = (int*)w;     w += (size_t)N * 4;
  int* deg = (int*)w;        w += (size_t)N * 4;
  int* csr = (int*)w;        w += (size_t)E * 4;
  int* bsum = (int*)w;       w += 256 * 4;
  int* gstart = (int*)w;     w += 128 * 4;
  float* partial = (float*)w; w += (size_t)B * 8 * D * 4;
  float* mvall = (float*)w;   w += (size_t)4 * B * D * 4;  // [4][64][512]
  (void)ws_size; (void)n_in; (void)out_size;

  (void)hipMemsetAsync(deg, 0, (size_t)N * 4, stream);
  f32_to_bf16_vec<<<(N * (D / 8) + 255) / 256, 256, 0, stream>>>(x, xb, N * (D / 8));
  for (int l = 0; l < 3; ++l) {
    transpose_bf16<<<dim3(8, 8), 256, 0, stream>>>(lin1_w + (size_t)l * D * D,
                                                   l1bt + (size_t)l * D * D);
    transpose_bf16<<<dim3(8, 8), 256, 0, stream>>>(lin2_w + (size_t)l * D * D,
                                                   l2bt + (size_t)l * D * D);
  }
  count_deg<<<(E + 255) / 256, 256, 0, stream>>>(dst, deg, E);
  scan_block<<<N / 256, 256, 0, stream>>>(deg, rowptr, bsum);
  scan_block<<<1, 256, 0, stream>>>(bsum, bsum, (int*)nullptr);
  scan_fixup<<<N / 256, 256, 0, stream>>>(rowptr, bsum, cursor, N, E);
  fill_csr<<<(E + 255) / 256, 256, 0, stream>>>(src, dst, cursor, csr, E);
  compute_gstart<<<(N + 255) / 256, 256, 0, stream>>>(batch, gstart, N, B);

  // stage 0: segmax(x)
  segmax_partial<<<dim3(B, 8), 256, 0, stream>>>(xb, gstart, partial);
  segmax_combine<<<B * D / 256, 256, 0, stream>>>(partial, mvall);

  for (int l = 0; l < 3; ++l) {
    agg_kernel<<<N / 4, 256, 0, stream>>>(xb, rowptr, csr, eps, l, hb);
    gemm_bias_leaky<<<dim3(D / GBN, N / GBM), 512, 0, stream>>>(
        hb, l1bt + (size_t)l * D * D, lin1_b + (size_t)l * D, tb, nullptr);
    gemm_bias_leaky<<<dim3(D / GBN, N / GBM), 512, 0, stream>>>(
        tb, l2bt + (size_t)l * D * D, lin2_b + (size_t)l * D, xb,
        (l == 2) ? xout : nullptr);
    segmax_partial<<<dim3(B, 8), 256, 0, stream>>>(xb, gstart, partial);
    segmax_combine<<<B * D / 256, 256, 0, stream>>>(partial,
                                                    mvall + (size_t)(l + 1) * B * D);
  }

  // batched pool projection: part = Sum_s mv[s] @ W_s + biases
  pool_gemm4<<<dim3(B, 2), 256, 0, stream>>>(mvall, proj_w, pool_w, proj_b,
                                             pool_b, part);
}

// Round 10
// 863.063 us; speedup vs baseline: 1.1233x; 1.1233x over previous
//
#include <hip/hip_runtime.h>

typedef unsigned int uint;
typedef unsigned short ushort;

#define D 512
#define GBM 256   // M-tile
#define GBN 256   // N-tile
#define GBK 64    // K-step

typedef __attribute__((ext_vector_type(8))) short bf16x8;
typedef __attribute__((ext_vector_type(4))) float f32x4;

__device__ __forceinline__ ushort f2b(float f) {
  uint u = __builtin_bit_cast(uint, f);
  return (ushort)((u + 0x7FFFu + ((u >> 16) & 1u)) >> 16);  // RNE
}
__device__ __forceinline__ float b_lo(uint u) { return __builtin_bit_cast(float, u << 16); }
__device__ __forceinline__ float b_hi(uint u) { return __builtin_bit_cast(float, u & 0xFFFF0000u); }

__device__ __forceinline__ void gload16(const void* g, void* l) {
  __builtin_amdgcn_global_load_lds((const __attribute__((address_space(1))) void*)g,
                                   (__attribute__((address_space(3))) void*)l, 16, 0, 0);
}

// ---------------- f32 -> bf16 bulk convert (8 elems/thread) ----------------
__global__ __launch_bounds__(256) void f32_to_bf16_vec(const float* __restrict__ in,
                                                       ushort* __restrict__ out, int n8) {
  const int i = blockIdx.x * 256 + threadIdx.x;
  if (i >= n8) return;
  const float4* p = (const float4*)in + (size_t)i * 2;
  float4 a = p[0], b = p[1];
  uint4 o;
  o.x = f2b(a.x) | ((uint)f2b(a.y) << 16);
  o.y = f2b(a.z) | ((uint)f2b(a.w) << 16);
  o.z = f2b(b.x) | ((uint)f2b(b.y) << 16);
  o.w = f2b(b.z) | ((uint)f2b(b.w) << 16);
  ((uint4*)out)[i] = o;
}

// ------------- transpose 512x512 f32 [k][o] -> bf16 BT [o][k] --------------
__global__ __launch_bounds__(256) void transpose_bf16(const float* __restrict__ W,
                                                      ushort* __restrict__ BT) {
  __shared__ float tile[64][65];
  const int bk = blockIdx.x * 64;  // k block
  const int bo = blockIdx.y * 64;  // o block
  const int tx = threadIdx.x & 63, ty = threadIdx.x >> 6;
#pragma unroll
  for (int r = 0; r < 64; r += 4)
    tile[r + ty][tx] = W[(size_t)(bk + r + ty) * D + bo + tx];
  __syncthreads();
#pragma unroll
  for (int r = 0; r < 64; r += 4)
    BT[(size_t)(bo + r + ty) * D + bk + tx] = f2b(tile[tx][r + ty]);
}

// ---------------------------- CSR build ------------------------------------
__global__ void count_deg(const int* __restrict__ dst, int* __restrict__ deg, int E) {
  const int e = blockIdx.x * 256 + threadIdx.x;
  if (e < E) atomicAdd(&deg[dst[e]], 1);
}

__global__ __launch_bounds__(256) void scan_block(const int* __restrict__ in,
                                                  int* __restrict__ out,
                                                  int* __restrict__ bsum) {
  __shared__ int sm[256];
  const int t = threadIdx.x;
  const int gi = blockIdx.x * 256 + t;
  const int v = in[gi];
  int x = v;
  sm[t] = x;
  __syncthreads();
#pragma unroll
  for (int off = 1; off < 256; off <<= 1) {
    const int y = (t >= off) ? sm[t - off] : 0;
    __syncthreads();
    x += y;
    sm[t] = x;
    __syncthreads();
  }
  out[gi] = x - v;  // exclusive
  if (t == 255 && bsum) bsum[blockIdx.x] = x;
}

__global__ void scan_fixup(int* __restrict__ rowptr, const int* __restrict__ bsum,
                           int* __restrict__ cursor, int N, int E) {
  const int i = blockIdx.x * 256 + threadIdx.x;
  const int r = rowptr[i] + bsum[i >> 8];
  rowptr[i] = r;
  cursor[i] = r;
  if (i == 0) rowptr[N] = E;
}

__global__ void fill_csr(const int* __restrict__ src, const int* __restrict__ dst,
                         int* __restrict__ cursor, int* __restrict__ csr, int E) {
  const int e = blockIdx.x * 256 + threadIdx.x;
  if (e >= E) return;
  const int pos = atomicAdd(&cursor[dst[e]], 1);
  csr[pos] = src[e];
}

// ------------------- graph start offsets (batch is sorted) -----------------
__global__ void compute_gstart(const int* __restrict__ batch, int* __restrict__ gstart,
                               int N, int B) {
  const int n = blockIdx.x * 256 + threadIdx.x;
  if (n >= N) return;
  const int b = batch[n];
  const int bp = (n == 0) ? -1 : batch[n - 1];
  for (int x = bp + 1; x <= b; ++x) gstart[x] = n;
  if (n == N - 1)
    for (int x = b + 1; x <= B; ++x) gstart[x] = N;
}

// --------------- GIN aggregation: h = (1+eps)*x + sum_nbr x ----------------
// At its random-gather structural floor (R2/R4/R7 evidence). Do not touch.
#define ACC8(v)                                          \
  a[0] += b_lo((v).x); a[1] += b_hi((v).x);              \
  a[2] += b_lo((v).y); a[3] += b_hi((v).y);              \
  a[4] += b_lo((v).z); a[5] += b_hi((v).z);              \
  a[6] += b_lo((v).w); a[7] += b_hi((v).w)

__global__ __launch_bounds__(256) void agg_kernel(const ushort* __restrict__ xb,
                                                  const int* __restrict__ rowptr,
                                                  const int* __restrict__ csr,
                                                  const float* __restrict__ eps_arr,
                                                  int layer, ushort* __restrict__ h) {
  const int node = blockIdx.x * 4 + (threadIdx.x >> 6);
  const int lane = threadIdx.x & 63;
  const float sc = 1.0f + eps_arr[layer];
  const size_t off = (size_t)lane * 8;
  const size_t base = (size_t)node * D + off;
  const uint4 u = *(const uint4*)(xb + base);
  float a[8];
  a[0] = b_lo(u.x) * sc; a[1] = b_hi(u.x) * sc;
  a[2] = b_lo(u.y) * sc; a[3] = b_hi(u.y) * sc;
  a[4] = b_lo(u.z) * sc; a[5] = b_hi(u.z) * sc;
  a[6] = b_lo(u.w) * sc; a[7] = b_hi(u.w) * sc;
  int e = rowptr[node];
  const int en = rowptr[node + 1];
  for (; e + 4 <= en; e += 4) {
    const int s0 = csr[e], s1 = csr[e + 1], s2 = csr[e + 2], s3 = csr[e + 3];
    const uint4 v0 = *(const uint4*)(xb + (size_t)s0 * D + off);
    const uint4 v1 = *(const uint4*)(xb + (size_t)s1 * D + off);
    const uint4 v2 = *(const uint4*)(xb + (size_t)s2 * D + off);
    const uint4 v3 = *(const uint4*)(xb + (size_t)s3 * D + off);
    ACC8(v0); ACC8(v1); ACC8(v2); ACC8(v3);
  }
  if (e + 2 <= en) {
    const int s0 = csr[e], s1 = csr[e + 1];
    const uint4 v0 = *(const uint4*)(xb + (size_t)s0 * D + off);
    const uint4 v1 = *(const uint4*)(xb + (size_t)s1 * D + off);
    ACC8(v0); ACC8(v1);
    e += 2;
  }
  if (e < en) {
    const uint4 v0 = *(const uint4*)(xb + (size_t)csr[e] * D + off);
    ACC8(v0);
  }
  uint4 o;
  o.x = f2b(a[0]) | ((uint)f2b(a[1]) << 16);
  o.y = f2b(a[2]) | ((uint)f2b(a[3]) << 16);
  o.z = f2b(a[4]) | ((uint)f2b(a[5]) << 16);
  o.w = f2b(a[6]) | ((uint)f2b(a[7]) << 16);
  *(uint4*)(h + base) = o;
}

// --------- bf16 GEMM: O = leaky(A @ BT^T + bias), 256² tile, BK=64 ---------
// R9-verified: raw s_barrier + COUNTED vmcnt(8) (T4) — never drains the
// prefetch in the main loop (~-9us/GEMM vs __syncthreads dbuf).
// Chunk-XOR swizzle (rule 21, both sides) as verified in R5-R9.
__global__ __launch_bounds__(512, 1) void gemm_bias_leaky(
    const ushort* __restrict__ A, const ushort* __restrict__ BT,
    const float* __restrict__ bias, ushort* __restrict__ Obf,
    float* __restrict__ Of32) {
  __shared__ alignas(16) ushort smem[4 * GBM * GBK];  // 128 KB: A0,B0,A1,B1
  ushort* const lA0 = smem;
  ushort* const lB0 = smem + GBM * GBK;
  ushort* const lA1 = smem + 2 * GBM * GBK;
  ushort* const lB1 = smem + 3 * GBM * GBK;

  const int tid = threadIdx.x;
  const int lane = tid & 63;
  const int wave = tid >> 6;
  const int wr = wave >> 2, wc = wave & 3;  // 2x4 waves; 128x64 out each

  // XCD swizzle (nwg = 512, divisible by 8 -> bijective):
  const int lin = blockIdx.y * gridDim.x + blockIdx.x;
  const int nwg = gridDim.x * gridDim.y;
  const int wg = (lin & 7) * (nwg >> 3) + (lin >> 3);
  const int n0 = (wg & 1) * GBN;
  const size_t m0 = (size_t)(wg >> 1) * GBM;

  // staging: issue i covers rows [i*64, i*64+64); thread tid -> linear LDS
  // 16B slot (i*512+tid); row%8 and source chunk invariant across i.
  const int srow0 = tid >> 3;                        // 0..63
  const int schunk = ((tid & 7) ^ (srow0 & 7)) * 8;  // swizzled global chunk

  f32x4 acc[8][4] = {};

  // fragment-read addressing
  const int rsel = lane & 15;
  const int g = lane >> 4;
  const int key = rsel & 7;

#define STAGE(bufA, bufB, kt)                                                     \
  {                                                                               \
    const int k0_ = (kt) * GBK;                                                   \
    _Pragma("unroll") for (int i_ = 0; i_ < 4; ++i_) {                            \
      const int row_ = i_ * 64 + srow0;                                           \
      gload16(A + (m0 + row_) * D + k0_ + schunk, &(bufA)[(i_ * 512 + wave * 64) * 8]); \
      gload16(BT + (size_t)(n0 + row_) * D + k0_ + schunk,                        \
              &(bufB)[(i_ * 512 + wave * 64) * 8]);                               \
    }                                                                             \
  }

#define COMPUTE(bufA, bufB)                                                       \
  {                                                                               \
    __builtin_amdgcn_s_setprio(1);                                                \
    _Pragma("unroll") for (int kk_ = 0; kk_ < 2; ++kk_) {                         \
      const int ch_ = ((kk_ * 4 + g) ^ key) * 8;                                  \
      bf16x8 af_[8], bf_[4];                                                      \
      _Pragma("unroll") for (int j_ = 0; j_ < 4; ++j_)                            \
          bf_[j_] = *(const bf16x8*)&(bufB)[(wc * 64 + j_ * 16 + rsel) * GBK + ch_]; \
      _Pragma("unroll") for (int i_ = 0; i_ < 8; ++i_)                            \
          af_[i_] = *(const bf16x8*)&(bufA)[(wr * 128 + i_ * 16 + rsel) * GBK + ch_]; \
      _Pragma("unroll") for (int i_ = 0; i_ < 8; ++i_)                            \
          _Pragma("unroll") for (int j_ = 0; j_ < 4; ++j_)                        \
              acc[i_][j_] = __builtin_amdgcn_mfma_f32_16x16x32_bf16(              \
                  af_[i_], bf_[j_], acc[i_][j_], 0, 0, 0);                        \
    }                                                                             \
    __builtin_amdgcn_s_setprio(0);                                                \
  }

#define VMW(N)                                              \
  asm volatile("s_waitcnt vmcnt(" #N ")" ::: "memory");     \
  __builtin_amdgcn_sched_barrier(0)
#define BAR() __builtin_amdgcn_s_barrier()

  // prologue + fully unrolled 8 K-tiles (K=512/GBK)
  STAGE(lA0, lB0, 0);
  STAGE(lA1, lB1, 1); VMW(8); BAR(); COMPUTE(lA0, lB0); BAR();  // t=0
  STAGE(lA0, lB0, 2); VMW(8); BAR(); COMPUTE(lA1, lB1); BAR();  // t=1
  STAGE(lA1, lB1, 3); VMW(8); BAR(); COMPUTE(lA0, lB0); BAR();  // t=2
  STAGE(lA0, lB0, 4); VMW(8); BAR(); COMPUTE(lA1, lB1); BAR();  // t=3
  STAGE(lA1, lB1, 5); VMW(8); BAR(); COMPUTE(lA0, lB0); BAR();  // t=4
  STAGE(lA0, lB0, 6); VMW(8); BAR(); COMPUTE(lA1, lB1); BAR();  // t=5
  STAGE(lA1, lB1, 7); VMW(8); BAR(); COMPUTE(lA0, lB0); BAR();  // t=6
  VMW(0); BAR(); COMPUTE(lA1, lB1);                             // t=7
#undef STAGE
#undef COMPUTE
#undef VMW
  __syncthreads();  // full drain before epilogue reuses smem

  // ---- epilogue: bias + leaky into LDS C-tile [256][256] bf16 (128 KB) ----
  // C/D layout: col=lane&15, row=(lane>>4)*4+reg (m89-verified)
#pragma unroll
  for (int j = 0; j < 4; ++j) {
    const int col = wc * 64 + j * 16 + rsel;
    const float bv = bias[n0 + col];
#pragma unroll
    for (int i = 0; i < 8; ++i) {
#pragma unroll
      for (int q = 0; q < 4; ++q) {
        const int row = wr * 128 + i * 16 + g * 4 + q;
        float v = acc[i][j][q] + bv;
        v = (v > 0.f) ? v : 0.01f * v;
        smem[row * GBN + col] = f2b(v);
      }
    }
  }
  __syncthreads();

  // ---- coalesced store: 32 chunks x 16B = 512B contiguous per row ----
#pragma unroll
  for (int it = 0; it < 16; ++it) {
    const int slot = it * 512 + tid;   // 8192 slots
    const int row = slot >> 5;
    const int chunk = slot & 31;
    const uint4 vv = *(const uint4*)&smem[row * GBN + chunk * 8];
    *(uint4*)(Obf + (m0 + row) * D + n0 + chunk * 8) = vv;
    if (Of32) {
      float4 f0, f1;
      f0.x = b_lo(vv.x); f0.y = b_hi(vv.x); f0.z = b_lo(vv.y); f0.w = b_hi(vv.y);
      f1.x = b_lo(vv.z); f1.y = b_hi(vv.z); f1.z = b_lo(vv.w); f1.w = b_hi(vv.w);
      float* op = Of32 + (m0 + row) * D + n0 + chunk * 8;
      *(float4*)op = f0;
      *(float4*)(op + 4) = f1;
    }
  }
}

// ------------------------- segment max (pooling) ---------------------------
__global__ __launch_bounds__(256) void segmax_partial(const ushort* __restrict__ xb,
                                                      const int* __restrict__ gstart,
                                                      float* __restrict__ partial) {
  const int g = blockIdx.x, s = blockIdx.y, t = threadIdx.x;
  const int st = gstart[g], en = gstart[g + 1];
  const long long cnt = en - st;
  const int lo = st + (int)((cnt * s) >> 3);
  const int hi = st + (int)((cnt * (s + 1)) >> 3);
  float m0 = -3.4e38f, m1 = -3.4e38f;
  for (int n = lo; n < hi; ++n) {
    const uint u = *(const uint*)(xb + (size_t)n * D + t * 2);
    m0 = fmaxf(m0, b_lo(u));
    m1 = fmaxf(m1, b_hi(u));
  }
  float* p = partial + (size_t)(g * 8 + s) * D + t * 2;
  p[0] = m0;
  p[1] = m1;
}

__global__ void segmax_combine(const float* __restrict__ partial, float* __restrict__ maxval) {
  const int i = blockIdx.x * 256 + threadIdx.x;  // < B*D
  const int g = i >> 9, d0 = i & (D - 1);
  float m = partial[(size_t)(g * 8) * D + d0];
#pragma unroll
  for (int s = 1; s < 8; ++s) m = fmaxf(m, partial[(size_t)(g * 8 + s) * D + d0]);
  maxval[i] = m;
}

// ------------- pool projection, split-K (R9 fused GEMV was latency-bound) --
// pp[slice][g][o], slice = s*4 + kq: partial over K-chunk [kq*128, kq*128+128)
// of stage s. 2048 blocks (vs R9's 128) -> latency covered; fixed-order
// reduction in pool_reduce keeps determinism.
__global__ __launch_bounds__(256) void pool_partial(
    const float* __restrict__ mv, const float* __restrict__ proj_w,
    const float* __restrict__ pool_w, float* __restrict__ pp) {
  const int g = blockIdx.x;                      // 64
  const int o = blockIdx.y * 256 + threadIdx.x;  // 2 x 256
  const int s = blockIdx.z >> 2, kq = blockIdx.z & 3;
  const float* W = (s == 0) ? proj_w : pool_w + (size_t)(s - 1) * D * D;
  const float* m = mv + ((size_t)s * 64 + g) * D + kq * 128;
  const float* Wp = W + (size_t)(kq * 128) * D + o;
  float acc = 0.f;
#pragma unroll 8
  for (int k = 0; k < 128; ++k) acc = fmaf(m[k], Wp[(size_t)k * D], acc);
  pp[((size_t)blockIdx.z * 64 + g) * D + o] = acc;
}

__global__ __launch_bounds__(256) void pool_reduce(
    const float* __restrict__ pp, const float* __restrict__ proj_b,
    const float* __restrict__ pool_b, float* __restrict__ part) {
  const int i = blockIdx.x * 256 + threadIdx.x;  // < 64*512
  const int g = i >> 9, o = i & (D - 1);
  float acc = proj_b[o] + pool_b[o] + pool_b[D + o] + pool_b[2 * D + o];
#pragma unroll
  for (int s = 0; s < 16; ++s) acc += pp[((size_t)s * 64 + g) * D + o];
  part[i] = acc;
}

// ---------------------------------------------------------------------------
extern "C" void kernel_launch(void* const* d_in, const int* in_sizes, int n_in,
                              void* d_out, int out_size, void* d_ws, size_t ws_size,
                              hipStream_t stream) {
  const float* x = (const float*)d_in[0];
  const int* ei = (const int*)d_in[1];
  const int* batch = (const int*)d_in[2];
  const float* proj_w = (const float*)d_in[3];
  const float* proj_b = (const float*)d_in[4];
  const float* lin1_w = (const float*)d_in[5];
  const float* lin1_b = (const float*)d_in[6];
  const float* lin2_w = (const float*)d_in[7];
  const float* lin2_b = (const float*)d_in[8];
  const float* eps = (const float*)d_in[9];
  const float* pool_w = (const float*)d_in[10];
  const float* pool_b = (const float*)d_in[11];

  const int N = in_sizes[0] / D;  // 65536
  const int E = in_sizes[1] / 2;  // 524288
  const int B = 64;
  const int* src = ei;
  const int* dst = ei + E;

  float* part = (float*)d_out;         // [64][512]
  float* xout = part + (size_t)B * D;  // [N][512]

  // workspace carve (~212 MB)
  char* w = (char*)d_ws;
  ushort* xb = (ushort*)w;   w += (size_t)N * D * 2;
  ushort* hb = (ushort*)w;   w += (size_t)N * D * 2;
  ushort* tb = (ushort*)w;   w += (size_t)N * D * 2;
  ushort* l1bt = (ushort*)w; w += (size_t)3 * D * D * 2;
  ushort* l2bt = (ushort*)w; w += (size_t)3 * D * D * 2;
  int* rowptr = (int*)w;     w += (size_t)(N + 4) * 4;
  int* cursor = (int*)w;     w += (size_t)N * 4;
  int* deg = (int*)w;        w += (size_t)N * 4;
  int* csr = (int*)w;        w += (size_t)E * 4;
  int* bsum = (int*)w;       w += 256 * 4;
  int* gstart = (int*)w;     w += 128 * 4;
  float* partial = (float*)w; w += (size_t)B * 8 * D * 4;
  float* mvall = (float*)w;   w += (size_t)4 * B * D * 4;   // [4][64][512]
  float* pp = (float*)w;      w += (size_t)16 * B * D * 4;  // [16][64][512]
  (void)ws_size; (void)n_in; (void)out_size;

  (void)hipMemsetAsync(deg, 0, (size_t)N * 4, stream);
  f32_to_bf16_vec<<<(N * (D / 8) + 255) / 256, 256, 0, stream>>>(x, xb, N * (D / 8));
  for (int l = 0; l < 3; ++l) {
    transpose_bf16<<<dim3(8, 8), 256, 0, stream>>>(lin1_w + (size_t)l * D * D,
                                                   l1bt + (size_t)l * D * D);
    transpose_bf16<<<dim3(8, 8), 256, 0, stream>>>(lin2_w + (size_t)l * D * D,
                                                   l2bt + (size_t)l * D * D);
  }
  count_deg<<<(E + 255) / 256, 256, 0, stream>>>(dst, deg, E);
  scan_block<<<N / 256, 256, 0, stream>>>(deg, rowptr, bsum);
  scan_block<<<1, 256, 0, stream>>>(bsum, bsum, (int*)nullptr);
  scan_fixup<<<N / 256, 256, 0, stream>>>(rowptr, bsum, cursor, N, E);
  fill_csr<<<(E + 255) / 256, 256, 0, stream>>>(src, dst, cursor, csr, E);
  compute_gstart<<<(N + 255) / 256, 256, 0, stream>>>(batch, gstart, N, B);

  // stage 0: segmax(x)
  segmax_partial<<<dim3(B, 8), 256, 0, stream>>>(xb, gstart, partial);
  segmax_combine<<<B * D / 256, 256, 0, stream>>>(partial, mvall);

  for (int l = 0; l < 3; ++l) {
    agg_kernel<<<N / 4, 256, 0, stream>>>(xb, rowptr, csr, eps, l, hb);
    gemm_bias_leaky<<<dim3(D / GBN, N / GBM), 512, 0, stream>>>(
        hb, l1bt + (size_t)l * D * D, lin1_b + (size_t)l * D, tb, nullptr);
    gemm_bias_leaky<<<dim3(D / GBN, N / GBM), 512, 0, stream>>>(
        tb, l2bt + (size_t)l * D * D, lin2_b + (size_t)l * D, xb,
        (l == 2) ? xout : nullptr);
    segmax_partial<<<dim3(B, 8), 256, 0, stream>>>(xb, gstart, partial);
    segmax_combine<<<B * D / 256, 256, 0, stream>>>(partial,
                                                    mvall + (size_t)(l + 1) * B * D);
  }

  // split-K pool projection
  pool_partial<<<dim3(B, 2, 16), 256, 0, stream>>>(mvall, proj_w, pool_w, pp);
  pool_reduce<<<B * D / 256, 256, 0, stream>>>(pp, proj_b, pool_b, part);
}

// Round 11
// 835.833 us; speedup vs baseline: 1.1599x; 1.0326x over previous
//
#include <hip/hip_runtime.h>

typedef unsigned int uint;
typedef unsigned short ushort;

#define D 512
#define TBM 128   // M-tile
#define TBN 256   // N-tile
#define TBK 32    // K-step

typedef __attribute__((ext_vector_type(8))) short bf16x8;
typedef __attribute__((ext_vector_type(4))) float f32x4;

__device__ __forceinline__ ushort f2b(float f) {
  uint u = __builtin_bit_cast(uint, f);
  return (ushort)((u + 0x7FFFu + ((u >> 16) & 1u)) >> 16);  // RNE
}
__device__ __forceinline__ float b_lo(uint u) { return __builtin_bit_cast(float, u << 16); }
__device__ __forceinline__ float b_hi(uint u) { return __builtin_bit_cast(float, u & 0xFFFF0000u); }

__device__ __forceinline__ void gload16(const void* g, void* l) {
  __builtin_amdgcn_global_load_lds((const __attribute__((address_space(1))) void*)g,
                                   (__attribute__((address_space(3))) void*)l, 16, 0, 0);
}

// ---------------- f32 -> bf16 bulk convert (8 elems/thread) ----------------
__global__ __launch_bounds__(256) void f32_to_bf16_vec(const float* __restrict__ in,
                                                       ushort* __restrict__ out, int n8) {
  const int i = blockIdx.x * 256 + threadIdx.x;
  if (i >= n8) return;
  const float4* p = (const float4*)in + (size_t)i * 2;
  float4 a = p[0], b = p[1];
  uint4 o;
  o.x = f2b(a.x) | ((uint)f2b(a.y) << 16);
  o.y = f2b(a.z) | ((uint)f2b(a.w) << 16);
  o.z = f2b(b.x) | ((uint)f2b(b.y) << 16);
  o.w = f2b(b.z) | ((uint)f2b(b.w) << 16);
  ((uint4*)out)[i] = o;
}

// ---- transpose all 6 weight mats: 512x512 f32 [k][o] -> bf16 BT [o][k] ----
__global__ __launch_bounds__(256) void transpose_all(const float* __restrict__ lin1_w,
                                                     const float* __restrict__ lin2_w,
                                                     ushort* __restrict__ l1bt,
                                                     ushort* __restrict__ l2bt) {
  __shared__ float tile[64][65];
  const int z = blockIdx.z, l = z >> 1;
  const float* W = ((z & 1) ? lin2_w : lin1_w) + (size_t)l * D * D;
  ushort* BT = ((z & 1) ? l2bt : l1bt) + (size_t)l * D * D;
  const int bk = blockIdx.x * 64;  // k block
  const int bo = blockIdx.y * 64;  // o block
  const int tx = threadIdx.x & 63, ty = threadIdx.x >> 6;
#pragma unroll
  for (int r = 0; r < 64; r += 4)
    tile[r + ty][tx] = W[(size_t)(bk + r + ty) * D + bo + tx];
  __syncthreads();
#pragma unroll
  for (int r = 0; r < 64; r += 4)
    BT[(size_t)(bo + r + ty) * D + bk + tx] = f2b(tile[tx][r + ty]);
}

// ---------------------------- CSR build ------------------------------------
__global__ void count_deg(const int* __restrict__ dst, int* __restrict__ deg, int E) {
  const int e = blockIdx.x * 256 + threadIdx.x;
  if (e < E) atomicAdd(&deg[dst[e]], 1);
}

__global__ __launch_bounds__(256) void scan_block(const int* __restrict__ in,
                                                  int* __restrict__ out,
                                                  int* __restrict__ bsum) {
  __shared__ int sm[256];
  const int t = threadIdx.x;
  const int gi = blockIdx.x * 256 + t;
  const int v = in[gi];
  int x = v;
  sm[t] = x;
  __syncthreads();
#pragma unroll
  for (int off = 1; off < 256; off <<= 1) {
    const int y = (t >= off) ? sm[t - off] : 0;
    __syncthreads();
    x += y;
    sm[t] = x;
    __syncthreads();
  }
  out[gi] = x - v;  // exclusive
  if (t == 255 && bsum) bsum[blockIdx.x] = x;
}

__global__ void scan_fixup(int* __restrict__ rowptr, const int* __restrict__ bsum,
                           int* __restrict__ cursor, int N, int E) {
  const int i = blockIdx.x * 256 + threadIdx.x;
  const int r = rowptr[i] + bsum[i >> 8];
  rowptr[i] = r;
  cursor[i] = r;
  if (i == 0) rowptr[N] = E;
}

__global__ void fill_csr(const int* __restrict__ src, const int* __restrict__ dst,
                         int* __restrict__ cursor, int* __restrict__ csr, int E) {
  const int e = blockIdx.x * 256 + threadIdx.x;
  if (e >= E) return;
  const int pos = atomicAdd(&cursor[dst[e]], 1);
  csr[pos] = src[e];
}

// ------------------- graph start offsets (batch is sorted) -----------------
__global__ void compute_gstart(const int* __restrict__ batch, int* __restrict__ gstart,
                               int N, int B) {
  const int n = blockIdx.x * 256 + threadIdx.x;
  if (n >= N) return;
  const int b = batch[n];
  const int bp = (n == 0) ? -1 : batch[n - 1];
  for (int x = bp + 1; x <= b; ++x) gstart[x] = n;
  if (n == N - 1)
    for (int x = b + 1; x <= B; ++x) gstart[x] = N;
}

// --------------- GIN aggregation: h = (1+eps)*x + sum_nbr x ----------------
// At its random-gather structural floor (R2/R4/R7 evidence). Do not touch.
#define ACC8(v)                                          \
  a[0] += b_lo((v).x); a[1] += b_hi((v).x);              \
  a[2] += b_lo((v).y); a[3] += b_hi((v).y);              \
  a[4] += b_lo((v).z); a[5] += b_hi((v).z);              \
  a[6] += b_lo((v).w); a[7] += b_hi((v).w)

__global__ __launch_bounds__(256) void agg_kernel(const ushort* __restrict__ xb,
                                                  const int* __restrict__ rowptr,
                                                  const int* __restrict__ csr,
                                                  const float* __restrict__ eps_arr,
                                                  int layer, ushort* __restrict__ h) {
  const int node = blockIdx.x * 4 + (threadIdx.x >> 6);
  const int lane = threadIdx.x & 63;
  const float sc = 1.0f + eps_arr[layer];
  const size_t off = (size_t)lane * 8;
  const size_t base = (size_t)node * D + off;
  const uint4 u = *(const uint4*)(xb + base);
  float a[8];
  a[0] = b_lo(u.x) * sc; a[1] = b_hi(u.x) * sc;
  a[2] = b_lo(u.y) * sc; a[3] = b_hi(u.y) * sc;
  a[4] = b_lo(u.z) * sc; a[5] = b_hi(u.z) * sc;
  a[6] = b_lo(u.w) * sc; a[7] = b_hi(u.w) * sc;
  int e = rowptr[node];
  const int en = rowptr[node + 1];
  for (; e + 4 <= en; e += 4) {
    const int s0 = csr[e], s1 = csr[e + 1], s2 = csr[e + 2], s3 = csr[e + 3];
    const uint4 v0 = *(const uint4*)(xb + (size_t)s0 * D + off);
    const uint4 v1 = *(const uint4*)(xb + (size_t)s1 * D + off);
    const uint4 v2 = *(const uint4*)(xb + (size_t)s2 * D + off);
    const uint4 v3 = *(const uint4*)(xb + (size_t)s3 * D + off);
    ACC8(v0); ACC8(v1); ACC8(v2); ACC8(v3);
  }
  if (e + 2 <= en) {
    const int s0 = csr[e], s1 = csr[e + 1];
    const uint4 v0 = *(const uint4*)(xb + (size_t)s0 * D + off);
    const uint4 v1 = *(const uint4*)(xb + (size_t)s1 * D + off);
    ACC8(v0); ACC8(v1);
    e += 2;
  }
  if (e < en) {
    const uint4 v0 = *(const uint4*)(xb + (size_t)csr[e] * D + off);
    ACC8(v0);
  }
  uint4 o;
  o.x = f2b(a[0]) | ((uint)f2b(a[1]) << 16);
  o.y = f2b(a[2]) | ((uint)f2b(a[3]) << 16);
  o.z = f2b(a[4]) | ((uint)f2b(a[5]) << 16);
  o.w = f2b(a[6]) | ((uint)f2b(a[7]) << 16);
  *(uint4*)(h + base) = o;
}

// ------ bf16 GEMM: O = leaky(A @ BT^T + bias), 128x256 tile, BK=32 ---------
// R11 redesign for OCCUPANCY: R9/R10's 256² kernel (128 KB LDS -> 1 block/CU,
// barrier-lockstep waves) measured ~6% MFMA-busy & 33% BW = latency-bound
// with no cross-phase overlap. This version: 48 KB LDS dbuf + VGPR<=128
// (launch_bounds(512,4)) -> 2 blocks/CU; one block's stage/epilogue overlaps
// the other's MFMA. T4 counted vmcnt kept: STAGE = 3 loads/thread (A 1, B 2),
// VMW(3) waits only the current tile, next tile's loads stay in flight.
// Chunk-XOR swizzle, 4 chunks/row: LDS[row][c] holds global chunk c^(row&3);
// staged via permuted GLOBAL source (linear gload_lds dest), read with the
// same XOR (key = rsel&3) -> conflict-free b128 fragment reads.
__global__ __launch_bounds__(512, 4) void gemm_bias_leaky(
    const ushort* __restrict__ A, const ushort* __restrict__ BT,
    const float* __restrict__ bias, ushort* __restrict__ Obf,
    float* __restrict__ Of32) {
  __shared__ alignas(16) ushort smem[24576];  // 48 KB
  ushort* const lA0 = smem;           // [128][32]  4096
  ushort* const lB0 = smem + 4096;    // [256][32]  8192
  ushort* const lA1 = smem + 12288;
  ushort* const lB1 = smem + 16384;

  const int tid = threadIdx.x;
  const int lane = tid & 63;
  const int wave = tid >> 6;
  const int wr = wave >> 2, wc = wave & 3;  // 2x4 waves; 64x64 out each

  // XCD swizzle (nwg = 2*512 = 1024, divisible by 8 -> bijective):
  const int lin = blockIdx.y * gridDim.x + blockIdx.x;
  const int nwg = gridDim.x * gridDim.y;
  const int wg = (lin & 7) * (nwg >> 3) + (lin >> 3);
  const int n0 = (wg & 1) * TBN;
  const size_t m0 = (size_t)(wg >> 1) * TBM;

  // staging: thread tid -> linear LDS 16B slot tid (A) / {tid, 512+tid} (B);
  // source row = slot>>2, source chunk = (slot&3) ^ (row&3).
  const int srow = tid >> 2;                        // 0..127
  const int schunk = ((tid & 3) ^ (srow & 3)) * 8;  // swizzled global chunk

  f32x4 acc[4][4] = {};

  // fragment-read addressing
  const int rsel = lane & 15;
  const int g = lane >> 4;
  const int ch = ((g ^ (rsel & 3))) * 8;  // swizzled chunk offset (ushorts)

#define STAGE(bufA, bufB, kt)                                                    \
  {                                                                              \
    const int k0_ = (kt) * TBK;                                                  \
    gload16(A + (m0 + srow) * D + k0_ + schunk, &(bufA)[tid * 8]);               \
    gload16(BT + (size_t)(n0 + srow) * D + k0_ + schunk, &(bufB)[tid * 8]);      \
    gload16(BT + (size_t)(n0 + 128 + srow) * D + k0_ + schunk,                   \
            &(bufB)[(512 + tid) * 8]);                                           \
  }

#define COMPUTE(bufA, bufB)                                                      \
  {                                                                              \
    __builtin_amdgcn_s_setprio(1);                                               \
    bf16x8 af_[4], bf_[4];                                                       \
    _Pragma("unroll") for (int j_ = 0; j_ < 4; ++j_)                             \
        bf_[j_] = *(const bf16x8*)&(bufB)[(wc * 64 + j_ * 16 + rsel) * TBK + ch];\
    _Pragma("unroll") for (int i_ = 0; i_ < 4; ++i_)                             \
        af_[i_] = *(const bf16x8*)&(bufA)[(wr * 64 + i_ * 16 + rsel) * TBK + ch];\
    _Pragma("unroll") for (int i_ = 0; i_ < 4; ++i_)                             \
        _Pragma("unroll") for (int j_ = 0; j_ < 4; ++j_)                         \
            acc[i_][j_] = __builtin_amdgcn_mfma_f32_16x16x32_bf16(               \
                af_[i_], bf_[j_], acc[i_][j_], 0, 0, 0);                         \
    __builtin_amdgcn_s_setprio(0);                                               \
  }

#define VMW(N)                                              \
  asm volatile("s_waitcnt vmcnt(" #N ")" ::: "memory");     \
  __builtin_amdgcn_sched_barrier(0)
#define BAR() __builtin_amdgcn_s_barrier()

  // K=512 -> 16 K-tiles; 2-buffer, stage-1-ahead, counted vmcnt(3).
  STAGE(lA0, lB0, 0);
  STAGE(lA1, lB1, 1);
#pragma unroll
  for (int tp = 0; tp < 8; ++tp) {
    VMW(3); BAR(); COMPUTE(lA0, lB0); BAR();
    if (tp < 7) STAGE(lA0, lB0, 2 * tp + 2);
    if (tp < 7) { VMW(3); } else { VMW(0); }
    BAR(); COMPUTE(lA1, lB1); BAR();
    if (tp < 7) STAGE(lA1, lB1, 2 * tp + 3);
  }
#undef STAGE
#undef COMPUTE
#undef VMW

  __syncthreads();  // drain before epilogue reuses smem

  // ---- epilogue via two 32 KB LDS half-tiles [64][256] bf16 ----
  // C/D layout: col=lane&15, row=(lane>>4)*4+reg (m89-verified)
  const int rbase = g * 4;
#pragma unroll
  for (int h = 0; h < 2; ++h) {
    if (wr == h) {
#pragma unroll
      for (int j = 0; j < 4; ++j) {
        const int col = wc * 64 + j * 16 + rsel;
        const float bv = bias[n0 + col];
#pragma unroll
        for (int i = 0; i < 4; ++i) {
#pragma unroll
          for (int q = 0; q < 4; ++q) {
            const int lrow = i * 16 + rbase + q;  // 0..63
            float v = acc[i][j][q] + bv;
            v = (v > 0.f) ? v : 0.01f * v;
            smem[lrow * TBN + col] = f2b(v);
          }
        }
      }
    }
    __syncthreads();
    // cooperative store: 64 rows x 512B contiguous
#pragma unroll
    for (int it = 0; it < 4; ++it) {
      const int slot = it * 512 + tid;  // 2048 slots
      const int row = slot >> 5;
      const int chunk = slot & 31;
      const uint4 vv = *(const uint4*)&smem[row * TBN + chunk * 8];
      const size_t grow = m0 + h * 64 + row;
      *(uint4*)(Obf + grow * D + n0 + chunk * 8) = vv;
      if (Of32) {
        float4 f0, f1;
        f0.x = b_lo(vv.x); f0.y = b_hi(vv.x); f0.z = b_lo(vv.y); f0.w = b_hi(vv.y);
        f1.x = b_lo(vv.z); f1.y = b_hi(vv.z); f1.z = b_lo(vv.w); f1.w = b_hi(vv.w);
        float* op = Of32 + grow * D + n0 + chunk * 8;
        *(float4*)op = f0;
        *(float4*)(op + 4) = f1;
      }
    }
    __syncthreads();
  }
}

// ------------------------- segment max (pooling) ---------------------------
__global__ __launch_bounds__(256) void segmax_partial(const ushort* __restrict__ xb,
                                                      const int* __restrict__ gstart,
                                                      float* __restrict__ partial) {
  const int g = blockIdx.x, s = blockIdx.y, t = threadIdx.x;
  const int st = gstart[g], en = gstart[g + 1];
  const long long cnt = en - st;
  const int lo = st + (int)((cnt * s) >> 3);
  const int hi = st + (int)((cnt * (s + 1)) >> 3);
  float m0 = -3.4e38f, m1 = -3.4e38f;
  for (int n = lo; n < hi; ++n) {
    const uint u = *(const uint*)(xb + (size_t)n * D + t * 2);
    m0 = fmaxf(m0, b_lo(u));
    m1 = fmaxf(m1, b_hi(u));
  }
  float* p = partial + (size_t)(g * 8 + s) * D + t * 2;
  p[0] = m0;
  p[1] = m1;
}

__global__ void segmax_combine(const float* __restrict__ partial, float* __restrict__ maxval) {
  const int i = blockIdx.x * 256 + threadIdx.x;  // < B*D
  const int g = i >> 9, d0 = i & (D - 1);
  float m = partial[(size_t)(g * 8) * D + d0];
#pragma unroll
  for (int s = 1; s < 8; ++s) m = fmaxf(m, partial[(size_t)(g * 8 + s) * D + d0]);
  maxval[i] = m;
}

// ------------- pool projection, split-K (R10-verified) ---------------------
__global__ __launch_bounds__(256) void pool_partial(
    const float* __restrict__ mv, const float* __restrict__ proj_w,
    const float* __restrict__ pool_w, float* __restrict__ pp) {
  const int g = blockIdx.x;                      // 64
  const int o = blockIdx.y * 256 + threadIdx.x;  // 2 x 256
  const int s = blockIdx.z >> 2, kq = blockIdx.z & 3;
  const float* W = (s == 0) ? proj_w : pool_w + (size_t)(s - 1) * D * D;
  const float* m = mv + ((size_t)s * 64 + g) * D + kq * 128;
  const float* Wp = W + (size_t)(kq * 128) * D + o;
  float acc = 0.f;
#pragma unroll 8
  for (int k = 0; k < 128; ++k) acc = fmaf(m[k], Wp[(size_t)k * D], acc);
  pp[((size_t)blockIdx.z * 64 + g) * D + o] = acc;
}

__global__ __launch_bounds__(256) void pool_reduce(
    const float* __restrict__ pp, const float* __restrict__ proj_b,
    const float* __restrict__ pool_b, float* __restrict__ part) {
  const int i = blockIdx.x * 256 + threadIdx.x;  // < 64*512
  const int g = i >> 9, o = i & (D - 1);
  float acc = proj_b[o] + pool_b[o] + pool_b[D + o] + pool_b[2 * D + o];
#pragma unroll
  for (int s = 0; s < 16; ++s) acc += pp[((size_t)s * 64 + g) * D + o];
  part[i] = acc;
}

// ---------------------------------------------------------------------------
extern "C" void kernel_launch(void* const* d_in, const int* in_sizes, int n_in,
                              void* d_out, int out_size, void* d_ws, size_t ws_size,
                              hipStream_t stream) {
  const float* x = (const float*)d_in[0];
  const int* ei = (const int*)d_in[1];
  const int* batch = (const int*)d_in[2];
  const float* proj_w = (const float*)d_in[3];
  const float* proj_b = (const float*)d_in[4];
  const float* lin1_w = (const float*)d_in[5];
  const float* lin1_b = (const float*)d_in[6];
  const float* lin2_w = (const float*)d_in[7];
  const float* lin2_b = (const float*)d_in[8];
  const float* eps = (const float*)d_in[9];
  const float* pool_w = (const float*)d_in[10];
  const float* pool_b = (const float*)d_in[11];

  const int N = in_sizes[0] / D;  // 65536
  const int E = in_sizes[1] / 2;  // 524288
  const int B = 64;
  const int* src = ei;
  const int* dst = ei + E;

  float* part = (float*)d_out;         // [64][512]
  float* xout = part + (size_t)B * D;  // [N][512]

  // workspace carve (~212 MB)
  char* w = (char*)d_ws;
  ushort* xb = (ushort*)w;   w += (size_t)N * D * 2;
  ushort* hb = (ushort*)w;   w += (size_t)N * D * 2;
  ushort* tb = (ushort*)w;   w += (size_t)N * D * 2;
  ushort* l1bt = (ushort*)w; w += (size_t)3 * D * D * 2;
  ushort* l2bt = (ushort*)w; w += (size_t)3 * D * D * 2;
  int* rowptr = (int*)w;     w += (size_t)(N + 4) * 4;
  int* cursor = (int*)w;     w += (size_t)N * 4;
  int* deg = (int*)w;        w += (size_t)N * 4;
  int* csr = (int*)w;        w += (size_t)E * 4;
  int* bsum = (int*)w;       w += 256 * 4;
  int* gstart = (int*)w;     w += 128 * 4;
  float* partial = (float*)w; w += (size_t)B * 8 * D * 4;
  float* mvall = (float*)w;   w += (size_t)4 * B * D * 4;   // [4][64][512]
  float* pp = (float*)w;      w += (size_t)16 * B * D * 4;  // [16][64][512]
  (void)ws_size; (void)n_in; (void)out_size;

  (void)hipMemsetAsync(deg, 0, (size_t)N * 4, stream);
  f32_to_bf16_vec<<<(N * (D / 8) + 255) / 256, 256, 0, stream>>>(x, xb, N * (D / 8));
  transpose_all<<<dim3(8, 8, 6), 256, 0, stream>>>(lin1_w, lin2_w, l1bt, l2bt);
  count_deg<<<(E + 255) / 256, 256, 0, stream>>>(dst, deg, E);
  scan_block<<<N / 256, 256, 0, stream>>>(deg, rowptr, bsum);
  scan_block<<<1, 256, 0, stream>>>(bsum, bsum, (int*)nullptr);
  scan_fixup<<<N / 256, 256, 0, stream>>>(rowptr, bsum, cursor, N, E);
  fill_csr<<<(E + 255) / 256, 256, 0, stream>>>(src, dst, cursor, csr, E);
  compute_gstart<<<(N + 255) / 256, 256, 0, stream>>>(batch, gstart, N, B);

  // stage 0: segmax(x)
  segmax_partial<<<dim3(B, 8), 256, 0, stream>>>(xb, gstart, partial);
  segmax_combine<<<B * D / 256, 256, 0, stream>>>(partial, mvall);

  for (int l = 0; l < 3; ++l) {
    agg_kernel<<<N / 4, 256, 0, stream>>>(xb, rowptr, csr, eps, l, hb);
    gemm_bias_leaky<<<dim3(D / TBN, N / TBM), 512, 0, stream>>>(
        hb, l1bt + (size_t)l * D * D, lin1_b + (size_t)l * D, tb, nullptr);
    gemm_bias_leaky<<<dim3(D / TBN, N / TBM), 512, 0, stream>>>(
        tb, l2bt + (size_t)l * D * D, lin2_b + (size_t)l * D, xb,
        (l == 2) ? xout : nullptr);
    segmax_partial<<<dim3(B, 8), 256, 0, stream>>>(xb, gstart, partial);
    segmax_combine<<<B * D / 256, 256, 0, stream>>>(partial,
                                                    mvall + (size_t)(l + 1) * B * D);
  }

  // split-K pool projection
  pool_partial<<<dim3(B, 2, 16), 256, 0, stream>>>(mvall, proj_w, pool_w, pp);
  pool_reduce<<<B * D / 256, 256, 0, stream>>>(pp, proj_b, pool_b, part);
}

// Round 12
// 758.894 us; speedup vs baseline: 1.2775x; 1.1014x over previous
//
#include <hip/hip_runtime.h>

typedef unsigned int uint;
typedef unsigned short ushort;

#define D 512
#define TBM 128   // M-tile
#define TBN 256   // N-tile
#define TBK 32    // K-step

typedef __attribute__((ext_vector_type(8))) short bf16x8;
typedef __attribute__((ext_vector_type(4))) float f32x4;

__device__ __forceinline__ ushort f2b(float f) {
  uint u = __builtin_bit_cast(uint, f);
  return (ushort)((u + 0x7FFFu + ((u >> 16) & 1u)) >> 16);  // RNE
}
__device__ __forceinline__ float b_lo(uint u) { return __builtin_bit_cast(float, u << 16); }
__device__ __forceinline__ float b_hi(uint u) { return __builtin_bit_cast(float, u & 0xFFFF0000u); }

// monotone float<->uint map: uint order == float order (for max via atomicMax)
__device__ __forceinline__ uint encf(float x) {
  uint u = __builtin_bit_cast(uint, x);
  return ((int)u >= 0) ? (u | 0x80000000u) : ~u;
}
__device__ __forceinline__ float decf(uint u) {
  return (u & 0x80000000u) ? __builtin_bit_cast(float, u ^ 0x80000000u)
                           : __builtin_bit_cast(float, ~u);
}

__device__ __forceinline__ void gload16(const void* g, void* l) {
  __builtin_amdgcn_global_load_lds((const __attribute__((address_space(1))) void*)g,
                                   (__attribute__((address_space(3))) void*)l, 16, 0, 0);
}

// ---------------- f32 -> bf16 bulk convert (8 elems/thread) ----------------
__global__ __launch_bounds__(256) void f32_to_bf16_vec(const float* __restrict__ in,
                                                       ushort* __restrict__ out, int n8) {
  const int i = blockIdx.x * 256 + threadIdx.x;
  if (i >= n8) return;
  const float4* p = (const float4*)in + (size_t)i * 2;
  float4 a = p[0], b = p[1];
  uint4 o;
  o.x = f2b(a.x) | ((uint)f2b(a.y) << 16);
  o.y = f2b(a.z) | ((uint)f2b(a.w) << 16);
  o.z = f2b(b.x) | ((uint)f2b(b.y) << 16);
  o.w = f2b(b.z) | ((uint)f2b(b.w) << 16);
  ((uint4*)out)[i] = o;
}

// ---- transpose all 6 weight mats: 512x512 f32 [k][o] -> bf16 BT [o][k] ----
__global__ __launch_bounds__(256) void transpose_all(const float* __restrict__ lin1_w,
                                                     const float* __restrict__ lin2_w,
                                                     ushort* __restrict__ l1bt,
                                                     ushort* __restrict__ l2bt) {
  __shared__ float tile[64][65];
  const int z = blockIdx.z, l = z >> 1;
  const float* W = ((z & 1) ? lin2_w : lin1_w) + (size_t)l * D * D;
  ushort* BT = ((z & 1) ? l2bt : l1bt) + (size_t)l * D * D;
  const int bk = blockIdx.x * 64;  // k block
  const int bo = blockIdx.y * 64;  // o block
  const int tx = threadIdx.x & 63, ty = threadIdx.x >> 6;
#pragma unroll
  for (int r = 0; r < 64; r += 4)
    tile[r + ty][tx] = W[(size_t)(bk + r + ty) * D + bo + tx];
  __syncthreads();
#pragma unroll
  for (int r = 0; r < 64; r += 4)
    BT[(size_t)(bo + r + ty) * D + bk + tx] = f2b(tile[tx][r + ty]);
}

// ---------------------------- CSR build ------------------------------------
__global__ void count_deg(const int* __restrict__ dst, int* __restrict__ deg, int E) {
  const int e = blockIdx.x * 256 + threadIdx.x;
  if (e < E) atomicAdd(&deg[dst[e]], 1);
}

__global__ __launch_bounds__(256) void scan_block(const int* __restrict__ in,
                                                  int* __restrict__ out,
                                                  int* __restrict__ bsum) {
  __shared__ int sm[256];
  const int t = threadIdx.x;
  const int gi = blockIdx.x * 256 + t;
  const int v = in[gi];
  int x = v;
  sm[t] = x;
  __syncthreads();
#pragma unroll
  for (int off = 1; off < 256; off <<= 1) {
    const int y = (t >= off) ? sm[t - off] : 0;
    __syncthreads();
    x += y;
    sm[t] = x;
    __syncthreads();
  }
  out[gi] = x - v;  // exclusive
  if (t == 255 && bsum) bsum[blockIdx.x] = x;
}

__global__ void scan_fixup(int* __restrict__ rowptr, const int* __restrict__ bsum,
                           int* __restrict__ cursor, int N, int E) {
  const int i = blockIdx.x * 256 + threadIdx.x;
  const int r = rowptr[i] + bsum[i >> 8];
  rowptr[i] = r;
  cursor[i] = r;
  if (i == 0) rowptr[N] = E;
}

__global__ void fill_csr(const int* __restrict__ src, const int* __restrict__ dst,
                         int* __restrict__ cursor, int* __restrict__ csr, int E) {
  const int e = blockIdx.x * 256 + threadIdx.x;
  if (e >= E) return;
  const int pos = atomicAdd(&cursor[dst[e]], 1);
  csr[pos] = src[e];
}

// ------------------- graph start offsets (batch is sorted) -----------------
__global__ void compute_gstart(const int* __restrict__ batch, int* __restrict__ gstart,
                               int N, int B) {
  const int n = blockIdx.x * 256 + threadIdx.x;
  if (n >= N) return;
  const int b = batch[n];
  const int bp = (n == 0) ? -1 : batch[n - 1];
  for (int x = bp + 1; x <= b; ++x) gstart[x] = n;
  if (n == N - 1)
    for (int x = b + 1; x <= B; ++x) gstart[x] = N;
}

// --------------- GIN aggregation: h = (1+eps)*x + sum_nbr x ----------------
// At its random-gather structural floor (R2/R4/R7 evidence). Do not touch.
#define ACC8(v)                                          \
  a[0] += b_lo((v).x); a[1] += b_hi((v).x);              \
  a[2] += b_lo((v).y); a[3] += b_hi((v).y);              \
  a[4] += b_lo((v).z); a[5] += b_hi((v).z);              \
  a[6] += b_lo((v).w); a[7] += b_hi((v).w)

__global__ __launch_bounds__(256) void agg_kernel(const ushort* __restrict__ xb,
                                                  const int* __restrict__ rowptr,
                                                  const int* __restrict__ csr,
                                                  const float* __restrict__ eps_arr,
                                                  int layer, ushort* __restrict__ h) {
  const int node = blockIdx.x * 4 + (threadIdx.x >> 6);
  const int lane = threadIdx.x & 63;
  const float sc = 1.0f + eps_arr[layer];
  const size_t off = (size_t)lane * 8;
  const size_t base = (size_t)node * D + off;
  const uint4 u = *(const uint4*)(xb + base);
  float a[8];
  a[0] = b_lo(u.x) * sc; a[1] = b_hi(u.x) * sc;
  a[2] = b_lo(u.y) * sc; a[3] = b_hi(u.y) * sc;
  a[4] = b_lo(u.z) * sc; a[5] = b_hi(u.z) * sc;
  a[6] = b_lo(u.w) * sc; a[7] = b_hi(u.w) * sc;
  int e = rowptr[node];
  const int en = rowptr[node + 1];
  for (; e + 4 <= en; e += 4) {
    const int s0 = csr[e], s1 = csr[e + 1], s2 = csr[e + 2], s3 = csr[e + 3];
    const uint4 v0 = *(const uint4*)(xb + (size_t)s0 * D + off);
    const uint4 v1 = *(const uint4*)(xb + (size_t)s1 * D + off);
    const uint4 v2 = *(const uint4*)(xb + (size_t)s2 * D + off);
    const uint4 v3 = *(const uint4*)(xb + (size_t)s3 * D + off);
    ACC8(v0); ACC8(v1); ACC8(v2); ACC8(v3);
  }
  if (e + 2 <= en) {
    const int s0 = csr[e], s1 = csr[e + 1];
    const uint4 v0 = *(const uint4*)(xb + (size_t)s0 * D + off);
    const uint4 v1 = *(const uint4*)(xb + (size_t)s1 * D + off);
    ACC8(v0); ACC8(v1);
    e += 2;
  }
  if (e < en) {
    const uint4 v0 = *(const uint4*)(xb + (size_t)csr[e] * D + off);
    ACC8(v0);
  }
  uint4 o;
  o.x = f2b(a[0]) | ((uint)f2b(a[1]) << 16);
  o.y = f2b(a[2]) | ((uint)f2b(a[3]) << 16);
  o.z = f2b(a[4]) | ((uint)f2b(a[5]) << 16);
  o.w = f2b(a[6]) | ((uint)f2b(a[7]) << 16);
  *(uint4*)(h + base) = o;
}

// ------ bf16 GEMM: O = leaky(A @ BT^T + bias), 128x256 tile, BK=32 ---------
// R11-verified occupancy structure (2 blocks/CU) + T4 counted vmcnt.
// NEW (R12): optional fused segment-max — while the C half-tile is still in
// LDS, each thread maxes its column over 32 rows (graph-boundary aware via
// batch[]) and flushes with atomicMax on a monotone uint encoding. Max is
// order-independent -> bit-exact determinism. Saves the 67MB re-read that a
// standalone segmax pass costs.
__global__ __launch_bounds__(512, 4) void gemm_bias_leaky(
    const ushort* __restrict__ A, const ushort* __restrict__ BT,
    const float* __restrict__ bias, ushort* __restrict__ Obf,
    float* __restrict__ Of32, const int* __restrict__ batch,
    uint* __restrict__ mvstage) {
  __shared__ alignas(16) ushort smem[24576];  // 48 KB
  ushort* const lA0 = smem;           // [128][32]  4096
  ushort* const lB0 = smem + 4096;    // [256][32]  8192
  ushort* const lA1 = smem + 12288;
  ushort* const lB1 = smem + 16384;

  const int tid = threadIdx.x;
  const int lane = tid & 63;
  const int wave = tid >> 6;
  const int wr = wave >> 2, wc = wave & 3;  // 2x4 waves; 64x64 out each

  // XCD swizzle (nwg = 2*512 = 1024, divisible by 8 -> bijective):
  const int lin = blockIdx.y * gridDim.x + blockIdx.x;
  const int nwg = gridDim.x * gridDim.y;
  const int wg = (lin & 7) * (nwg >> 3) + (lin >> 3);
  const int n0 = (wg & 1) * TBN;
  const size_t m0 = (size_t)(wg >> 1) * TBM;

  // staging: thread tid -> linear LDS 16B slot tid (A) / {tid, 512+tid} (B);
  // source row = slot>>2, source chunk = (slot&3) ^ (row&3).
  const int srow = tid >> 2;                        // 0..127
  const int schunk = ((tid & 3) ^ (srow & 3)) * 8;  // swizzled global chunk

  f32x4 acc[4][4] = {};

  // fragment-read addressing
  const int rsel = lane & 15;
  const int g = lane >> 4;
  const int ch = ((g ^ (rsel & 3))) * 8;  // swizzled chunk offset (ushorts)

#define STAGE(bufA, bufB, kt)                                                    \
  {                                                                              \
    const int k0_ = (kt) * TBK;                                                  \
    gload16(A + (m0 + srow) * D + k0_ + schunk, &(bufA)[tid * 8]);               \
    gload16(BT + (size_t)(n0 + srow) * D + k0_ + schunk, &(bufB)[tid * 8]);      \
    gload16(BT + (size_t)(n0 + 128 + srow) * D + k0_ + schunk,                   \
            &(bufB)[(512 + tid) * 8]);                                           \
  }

#define COMPUTE(bufA, bufB)                                                      \
  {                                                                              \
    __builtin_amdgcn_s_setprio(1);                                               \
    bf16x8 af_[4], bf_[4];                                                       \
    _Pragma("unroll") for (int j_ = 0; j_ < 4; ++j_)                             \
        bf_[j_] = *(const bf16x8*)&(bufB)[(wc * 64 + j_ * 16 + rsel) * TBK + ch];\
    _Pragma("unroll") for (int i_ = 0; i_ < 4; ++i_)                             \
        af_[i_] = *(const bf16x8*)&(bufA)[(wr * 64 + i_ * 16 + rsel) * TBK + ch];\
    _Pragma("unroll") for (int i_ = 0; i_ < 4; ++i_)                             \
        _Pragma("unroll") for (int j_ = 0; j_ < 4; ++j_)                         \
            acc[i_][j_] = __builtin_amdgcn_mfma_f32_16x16x32_bf16(               \
                af_[i_], bf_[j_], acc[i_][j_], 0, 0, 0);                         \
    __builtin_amdgcn_s_setprio(0);                                               \
  }

#define VMW(N)                                              \
  asm volatile("s_waitcnt vmcnt(" #N ")" ::: "memory");     \
  __builtin_amdgcn_sched_barrier(0)
#define BAR() __builtin_amdgcn_s_barrier()

  // K=512 -> 16 K-tiles; 2-buffer, stage-1-ahead, counted vmcnt(3).
  STAGE(lA0, lB0, 0);
  STAGE(lA1, lB1, 1);
#pragma unroll
  for (int tp = 0; tp < 8; ++tp) {
    VMW(3); BAR(); COMPUTE(lA0, lB0); BAR();
    if (tp < 7) STAGE(lA0, lB0, 2 * tp + 2);
    if (tp < 7) { VMW(3); } else { VMW(0); }
    BAR(); COMPUTE(lA1, lB1); BAR();
    if (tp < 7) STAGE(lA1, lB1, 2 * tp + 3);
  }
#undef STAGE
#undef COMPUTE
#undef VMW

  __syncthreads();  // drain before epilogue reuses smem

  // ---- epilogue via two 32 KB LDS half-tiles [64][256] bf16 ----
  // C/D layout: col=lane&15, row=(lane>>4)*4+reg (m89-verified)
  const int rbase = g * 4;
#pragma unroll
  for (int h = 0; h < 2; ++h) {
    if (wr == h) {
#pragma unroll
      for (int j = 0; j < 4; ++j) {
        const int col = wc * 64 + j * 16 + rsel;
        const float bv = bias[n0 + col];
#pragma unroll
        for (int i = 0; i < 4; ++i) {
#pragma unroll
          for (int q = 0; q < 4; ++q) {
            const int lrow = i * 16 + rbase + q;  // 0..63
            float v = acc[i][j][q] + bv;
            v = (v > 0.f) ? v : 0.01f * v;
            smem[lrow * TBN + col] = f2b(v);
          }
        }
      }
    }
    __syncthreads();
    // cooperative store: 64 rows x 512B contiguous
#pragma unroll
    for (int it = 0; it < 4; ++it) {
      const int slot = it * 512 + tid;  // 2048 slots
      const int row = slot >> 5;
      const int chunk = slot & 31;
      const uint4 vv = *(const uint4*)&smem[row * TBN + chunk * 8];
      const size_t grow = m0 + h * 64 + row;
      *(uint4*)(Obf + grow * D + n0 + chunk * 8) = vv;
      if (Of32) {
        float4 f0, f1;
        f0.x = b_lo(vv.x); f0.y = b_hi(vv.x); f0.z = b_lo(vv.y); f0.w = b_hi(vv.y);
        f1.x = b_lo(vv.z); f1.y = b_hi(vv.z); f1.z = b_lo(vv.w); f1.w = b_hi(vv.w);
        float* op = Of32 + grow * D + n0 + chunk * 8;
        *(float4*)op = f0;
        *(float4*)(op + 4) = f1;
      }
    }
    // fused segment-max over this half-tile (still resident in LDS)
    if (mvstage) {
      const int col = tid & 255;          // 0..255 within n0 slice
      const int rh = tid >> 8;            // 0/1: rows rh*32..rh*32+31
      const size_t rowbase = m0 + h * 64 + rh * 32;
      float mx = -3.4e38f;
      int curg = batch[rowbase];
#pragma unroll 4
      for (int r = 0; r < 32; ++r) {
        const int gg = batch[rowbase + r];
        if (gg != curg) {
          atomicMax(&mvstage[(size_t)curg * D + n0 + col], encf(mx));
          mx = -3.4e38f;
          curg = gg;
        }
        mx = fmaxf(mx, b_lo((uint)smem[(rh * 32 + r) * TBN + col]));
      }
      atomicMax(&mvstage[(size_t)curg * D + n0 + col], encf(mx));
    }
    __syncthreads();
  }
}

// ------------------- segment max (stage 0 / initial x only) ----------------
__global__ __launch_bounds__(256) void segmax_partial(const ushort* __restrict__ xb,
                                                      const int* __restrict__ gstart,
                                                      float* __restrict__ partial) {
  const int g = blockIdx.x, s = blockIdx.y, t = threadIdx.x;
  const int st = gstart[g], en = gstart[g + 1];
  const long long cnt = en - st;
  const int lo = st + (int)((cnt * s) >> 3);
  const int hi = st + (int)((cnt * (s + 1)) >> 3);
  float m0 = -3.4e38f, m1 = -3.4e38f;
  for (int n = lo; n < hi; ++n) {
    const uint u = *(const uint*)(xb + (size_t)n * D + t * 2);
    m0 = fmaxf(m0, b_lo(u));
    m1 = fmaxf(m1, b_hi(u));
  }
  float* p = partial + (size_t)(g * 8 + s) * D + t * 2;
  p[0] = m0;
  p[1] = m1;
}

__global__ void segmax_combine(const float* __restrict__ partial, uint* __restrict__ maxval) {
  const int i = blockIdx.x * 256 + threadIdx.x;  // < B*D
  const int g = i >> 9, d0 = i & (D - 1);
  float m = partial[(size_t)(g * 8) * D + d0];
#pragma unroll
  for (int s = 1; s < 8; ++s) m = fmaxf(m, partial[(size_t)(g * 8 + s) * D + d0]);
  maxval[i] = encf(m);  // encoded, consistent with fused-atomic stages
}

// ------------- pool projection, split-K (R10-verified); mv is ENCODED ------
__global__ __launch_bounds__(256) void pool_partial(
    const uint* __restrict__ mv, const float* __restrict__ proj_w,
    const float* __restrict__ pool_w, float* __restrict__ pp) {
  const int g = blockIdx.x;                      // 64
  const int o = blockIdx.y * 256 + threadIdx.x;  // 2 x 256
  const int s = blockIdx.z >> 2, kq = blockIdx.z & 3;
  const float* W = (s == 0) ? proj_w : pool_w + (size_t)(s - 1) * D * D;
  const uint* m = mv + ((size_t)s * 64 + g) * D + kq * 128;
  const float* Wp = W + (size_t)(kq * 128) * D + o;
  float acc = 0.f;
#pragma unroll 8
  for (int k = 0; k < 128; ++k) acc = fmaf(decf(m[k]), Wp[(size_t)k * D], acc);
  pp[((size_t)blockIdx.z * 64 + g) * D + o] = acc;
}

__global__ __launch_bounds__(256) void pool_reduce(
    const float* __restrict__ pp, const float* __restrict__ proj_b,
    const float* __restrict__ pool_b, float* __restrict__ part) {
  const int i = blockIdx.x * 256 + threadIdx.x;  // < 64*512
  const int g = i >> 9, o = i & (D - 1);
  float acc = proj_b[o] + pool_b[o] + pool_b[D + o] + pool_b[2 * D + o];
#pragma unroll
  for (int s = 0; s < 16; ++s) acc += pp[((size_t)s * 64 + g) * D + o];
  part[i] = acc;
}

// ---------------------------------------------------------------------------
extern "C" void kernel_launch(void* const* d_in, const int* in_sizes, int n_in,
                              void* d_out, int out_size, void* d_ws, size_t ws_size,
                              hipStream_t stream) {
  const float* x = (const float*)d_in[0];
  const int* ei = (const int*)d_in[1];
  const int* batch = (const int*)d_in[2];
  const float* proj_w = (const float*)d_in[3];
  const float* proj_b = (const float*)d_in[4];
  const float* lin1_w = (const float*)d_in[5];
  const float* lin1_b = (const float*)d_in[6];
  const float* lin2_w = (const float*)d_in[7];
  const float* lin2_b = (const float*)d_in[8];
  const float* eps = (const float*)d_in[9];
  const float* pool_w = (const float*)d_in[10];
  const float* pool_b = (const float*)d_in[11];

  const int N = in_sizes[0] / D;  // 65536
  const int E = in_sizes[1] / 2;  // 524288
  const int B = 64;
  const int* src = ei;
  const int* dst = ei + E;

  float* part = (float*)d_out;         // [64][512]
  float* xout = part + (size_t)B * D;  // [N][512]

  // workspace carve (~212 MB)
  char* w = (char*)d_ws;
  ushort* xb = (ushort*)w;   w += (size_t)N * D * 2;
  ushort* hb = (ushort*)w;   w += (size_t)N * D * 2;
  ushort* tb = (ushort*)w;   w += (size_t)N * D * 2;
  ushort* l1bt = (ushort*)w; w += (size_t)3 * D * D * 2;
  ushort* l2bt = (ushort*)w; w += (size_t)3 * D * D * 2;
  int* rowptr = (int*)w;     w += (size_t)(N + 4) * 4;
  int* cursor = (int*)w;     w += (size_t)N * 4;
  int* deg = (int*)w;        w += (size_t)N * 4;
  int* csr = (int*)w;        w += (size_t)E * 4;
  int* bsum = (int*)w;       w += 256 * 4;
  int* gstart = (int*)w;     w += 128 * 4;
  float* partial = (float*)w; w += (size_t)B * 8 * D * 4;
  uint* mvall = (uint*)w;     w += (size_t)4 * B * D * 4;   // [4][64][512] encoded
  float* pp = (float*)w;      w += (size_t)16 * B * D * 4;  // [16][64][512]
  (void)ws_size; (void)n_in; (void)out_size;

  (void)hipMemsetAsync(deg, 0, (size_t)N * 4, stream);
  (void)hipMemsetAsync(mvall + (size_t)B * D, 0, (size_t)3 * B * D * 4, stream);
  f32_to_bf16_vec<<<(N * (D / 8) + 255) / 256, 256, 0, stream>>>(x, xb, N * (D / 8));
  transpose_all<<<dim3(8, 8, 6), 256, 0, stream>>>(lin1_w, lin2_w, l1bt, l2bt);
  count_deg<<<(E + 255) / 256, 256, 0, stream>>>(dst, deg, E);
  scan_block<<<N / 256, 256, 0, stream>>>(deg, rowptr, bsum);
  scan_block<<<1, 256, 0, stream>>>(bsum, bsum, (int*)nullptr);
  scan_fixup<<<N / 256, 256, 0, stream>>>(rowptr, bsum, cursor, N, E);
  fill_csr<<<(E + 255) / 256, 256, 0, stream>>>(src, dst, cursor, csr, E);
  compute_gstart<<<(N + 255) / 256, 256, 0, stream>>>(batch, gstart, N, B);

  // stage 0: segmax(x) (standalone; writes encoded)
  segmax_partial<<<dim3(B, 8), 256, 0, stream>>>(xb, gstart, partial);
  segmax_combine<<<B * D / 256, 256, 0, stream>>>(partial, mvall);

  for (int l = 0; l < 3; ++l) {
    agg_kernel<<<N / 4, 256, 0, stream>>>(xb, rowptr, csr, eps, l, hb);
    gemm_bias_leaky<<<dim3(D / TBN, N / TBM), 512, 0, stream>>>(
        hb, l1bt + (size_t)l * D * D, lin1_b + (size_t)l * D, tb, nullptr,
        batch, nullptr);
    gemm_bias_leaky<<<dim3(D / TBN, N / TBM), 512, 0, stream>>>(
        tb, l2bt + (size_t)l * D * D, lin2_b + (size_t)l * D, xb,
        (l == 2) ? xout : nullptr, batch,
        mvall + (size_t)(l + 1) * B * D);  // fused segmax stage l+1
  }

  // split-K pool projection (decodes mvall)
  pool_partial<<<dim3(B, 2, 16), 256, 0, stream>>>(mvall, proj_w, pool_w, pp);
  pool_reduce<<<B * D / 256, 256, 0, stream>>>(pp, proj_b, pool_b, part);
}

// Round 13
// 743.530 us; speedup vs baseline: 1.3039x; 1.0207x over previous
//
#include <hip/hip_runtime.h>

typedef unsigned int uint;
typedef unsigned short ushort;

#define D 512
#define TBM 128   // M-tile
#define TBN 256   // N-tile
#define TBK 32    // K-step

typedef __attribute__((ext_vector_type(8))) short bf16x8;
typedef __attribute__((ext_vector_type(4))) float f32x4;

__device__ __forceinline__ ushort f2b(float f) {
  uint u = __builtin_bit_cast(uint, f);
  return (ushort)((u + 0x7FFFu + ((u >> 16) & 1u)) >> 16);  // RNE
}
__device__ __forceinline__ float b_lo(uint u) { return __builtin_bit_cast(float, u << 16); }
__device__ __forceinline__ float b_hi(uint u) { return __builtin_bit_cast(float, u & 0xFFFF0000u); }

// monotone float<->uint map: uint order == float order (for max via atomicMax)
__device__ __forceinline__ uint encf(float x) {
  uint u = __builtin_bit_cast(uint, x);
  return ((int)u >= 0) ? (u | 0x80000000u) : ~u;
}
__device__ __forceinline__ float decf(uint u) {
  return (u & 0x80000000u) ? __builtin_bit_cast(float, u ^ 0x80000000u)
                           : __builtin_bit_cast(float, ~u);
}

__device__ __forceinline__ void gload16(const void* g, void* l) {
  __builtin_amdgcn_global_load_lds((const __attribute__((address_space(1))) void*)g,
                                   (__attribute__((address_space(3))) void*)l, 16, 0, 0);
}

// ---- f32 -> bf16 convert + FUSED stage-0 segment-max (R13) ----------------
// 512 blocks x 256 thr; block = rows [b*128, b*128+128). Thread t: col-chunk
// c = t&63 (8 elems), row-subset rsub = t>>6 (rows rsub, rsub+4, ...).
// Wave = 64 chunks of one row -> coalesced 2KB reads / 1KB writes. Running
// 8-wide max per thread, graph-boundary flush via encoded atomicMax
// (order-free -> bit-exact; ~1.2M atomics total, fill_csr scale).
__global__ __launch_bounds__(256) void f32_to_bf16_segmax(
    const float* __restrict__ in, ushort* __restrict__ out,
    const int* __restrict__ batch, uint* __restrict__ mv0) {
  const int t = threadIdx.x;
  const int chunk = t & 63;
  const int rsub = t >> 6;
  const int row0 = blockIdx.x * 128;
  float mx[8];
#pragma unroll
  for (int j = 0; j < 8; ++j) mx[j] = -3.4e38f;
  int curg = batch[row0 + rsub];
#pragma unroll 4
  for (int k = 0; k < 32; ++k) {
    const int row = row0 + rsub + k * 4;
    const int gg = batch[row];
    if (gg != curg) {
#pragma unroll
      for (int j = 0; j < 8; ++j)
        atomicMax(&mv0[(size_t)curg * D + chunk * 8 + j], encf(mx[j]));
#pragma unroll
      for (int j = 0; j < 8; ++j) mx[j] = -3.4e38f;
      curg = gg;
    }
    const float4* p = (const float4*)(in + (size_t)row * D + chunk * 8);
    const float4 a = p[0], b = p[1];
    float v[8] = {a.x, a.y, a.z, a.w, b.x, b.y, b.z, b.w};
    uint4 o;
    o.x = f2b(v[0]) | ((uint)f2b(v[1]) << 16);
    o.y = f2b(v[2]) | ((uint)f2b(v[3]) << 16);
    o.z = f2b(v[4]) | ((uint)f2b(v[5]) << 16);
    o.w = f2b(v[6]) | ((uint)f2b(v[7]) << 16);
    *(uint4*)(out + (size_t)row * D + chunk * 8) = o;
#pragma unroll
    for (int j = 0; j < 8; ++j) mx[j] = fmaxf(mx[j], v[j]);
  }
#pragma unroll
  for (int j = 0; j < 8; ++j)
    atomicMax(&mv0[(size_t)curg * D + chunk * 8 + j], encf(mx[j]));
}

// ---- transpose all 6 weight mats: 512x512 f32 [k][o] -> bf16 BT [o][k] ----
__global__ __launch_bounds__(256) void transpose_all(const float* __restrict__ lin1_w,
                                                     const float* __restrict__ lin2_w,
                                                     ushort* __restrict__ l1bt,
                                                     ushort* __restrict__ l2bt) {
  __shared__ float tile[64][65];
  const int z = blockIdx.z, l = z >> 1;
  const float* W = ((z & 1) ? lin2_w : lin1_w) + (size_t)l * D * D;
  ushort* BT = ((z & 1) ? l2bt : l1bt) + (size_t)l * D * D;
  const int bk = blockIdx.x * 64;  // k block
  const int bo = blockIdx.y * 64;  // o block
  const int tx = threadIdx.x & 63, ty = threadIdx.x >> 6;
#pragma unroll
  for (int r = 0; r < 64; r += 4)
    tile[r + ty][tx] = W[(size_t)(bk + r + ty) * D + bo + tx];
  __syncthreads();
#pragma unroll
  for (int r = 0; r < 64; r += 4)
    BT[(size_t)(bo + r + ty) * D + bk + tx] = f2b(tile[tx][r + ty]);
}

// ---------------------------- CSR build ------------------------------------
__global__ void count_deg(const int* __restrict__ dst, int* __restrict__ deg, int E) {
  const int e = blockIdx.x * 256 + threadIdx.x;
  if (e < E) atomicAdd(&deg[dst[e]], 1);
}

__global__ __launch_bounds__(256) void scan_block(const int* __restrict__ in,
                                                  int* __restrict__ out,
                                                  int* __restrict__ bsum) {
  __shared__ int sm[256];
  const int t = threadIdx.x;
  const int gi = blockIdx.x * 256 + t;
  const int v = in[gi];
  int x = v;
  sm[t] = x;
  __syncthreads();
#pragma unroll
  for (int off = 1; off < 256; off <<= 1) {
    const int y = (t >= off) ? sm[t - off] : 0;
    __syncthreads();
    x += y;
    sm[t] = x;
    __syncthreads();
  }
  out[gi] = x - v;  // exclusive
  if (t == 255 && bsum) bsum[blockIdx.x] = x;
}

__global__ void scan_fixup(int* __restrict__ rowptr, const int* __restrict__ bsum,
                           int* __restrict__ cursor, int N, int E) {
  const int i = blockIdx.x * 256 + threadIdx.x;
  const int r = rowptr[i] + bsum[i >> 8];
  rowptr[i] = r;
  cursor[i] = r;
  if (i == 0) rowptr[N] = E;
}

__global__ void fill_csr(const int* __restrict__ src, const int* __restrict__ dst,
                         int* __restrict__ cursor, int* __restrict__ csr, int E) {
  const int e = blockIdx.x * 256 + threadIdx.x;
  if (e >= E) return;
  const int pos = atomicAdd(&cursor[dst[e]], 1);
  csr[pos] = src[e];
}

// --------------- GIN aggregation: h = (1+eps)*x + sum_nbr x ----------------
// At its random-gather structural floor (R2/R4/R7 evidence). Do not touch.
#define ACC8(v)                                          \
  a[0] += b_lo((v).x); a[1] += b_hi((v).x);              \
  a[2] += b_lo((v).y); a[3] += b_hi((v).y);              \
  a[4] += b_lo((v).z); a[5] += b_hi((v).z);              \
  a[6] += b_lo((v).w); a[7] += b_hi((v).w)

__global__ __launch_bounds__(256) void agg_kernel(const ushort* __restrict__ xb,
                                                  const int* __restrict__ rowptr,
                                                  const int* __restrict__ csr,
                                                  const float* __restrict__ eps_arr,
                                                  int layer, ushort* __restrict__ h) {
  const int node = blockIdx.x * 4 + (threadIdx.x >> 6);
  const int lane = threadIdx.x & 63;
  const float sc = 1.0f + eps_arr[layer];
  const size_t off = (size_t)lane * 8;
  const size_t base = (size_t)node * D + off;
  const uint4 u = *(const uint4*)(xb + base);
  float a[8];
  a[0] = b_lo(u.x) * sc; a[1] = b_hi(u.x) * sc;
  a[2] = b_lo(u.y) * sc; a[3] = b_hi(u.y) * sc;
  a[4] = b_lo(u.z) * sc; a[5] = b_hi(u.z) * sc;
  a[6] = b_lo(u.w) * sc; a[7] = b_hi(u.w) * sc;
  int e = rowptr[node];
  const int en = rowptr[node + 1];
  for (; e + 4 <= en; e += 4) {
    const int s0 = csr[e], s1 = csr[e + 1], s2 = csr[e + 2], s3 = csr[e + 3];
    const uint4 v0 = *(const uint4*)(xb + (size_t)s0 * D + off);
    const uint4 v1 = *(const uint4*)(xb + (size_t)s1 * D + off);
    const uint4 v2 = *(const uint4*)(xb + (size_t)s2 * D + off);
    const uint4 v3 = *(const uint4*)(xb + (size_t)s3 * D + off);
    ACC8(v0); ACC8(v1); ACC8(v2); ACC8(v3);
  }
  if (e + 2 <= en) {
    const int s0 = csr[e], s1 = csr[e + 1];
    const uint4 v0 = *(const uint4*)(xb + (size_t)s0 * D + off);
    const uint4 v1 = *(const uint4*)(xb + (size_t)s1 * D + off);
    ACC8(v0); ACC8(v1);
    e += 2;
  }
  if (e < en) {
    const uint4 v0 = *(const uint4*)(xb + (size_t)csr[e] * D + off);
    ACC8(v0);
  }
  uint4 o;
  o.x = f2b(a[0]) | ((uint)f2b(a[1]) << 16);
  o.y = f2b(a[2]) | ((uint)f2b(a[3]) << 16);
  o.z = f2b(a[4]) | ((uint)f2b(a[5]) << 16);
  o.w = f2b(a[6]) | ((uint)f2b(a[7]) << 16);
  *(uint4*)(h + base) = o;
}

// ------ bf16 GEMM: O = leaky(A @ BT^T + bias), 128x256 tile, BK=32 ---------
// R11/R12 base (2 blocks/CU, counted vmcnt, chunk-XOR swizzle, fused segmax)
// R13: 3-buffer, 2-tile-ahead pipeline (72 KB LDS, still 2 blocks/CU).
// Steady state: 3 stages (9 loads/thread) in flight; VMW(6) releases only the
// oldest tile. Post-compute BAR protects buffer b before STAGE(t+3) (same b).
__global__ __launch_bounds__(512, 4) void gemm_bias_leaky(
    const ushort* __restrict__ A, const ushort* __restrict__ BT,
    const float* __restrict__ bias, ushort* __restrict__ Obf,
    float* __restrict__ Of32, const int* __restrict__ batch,
    uint* __restrict__ mvstage) {
  __shared__ alignas(16) ushort smem[36864];  // 72 KB
  ushort* const lA0 = smem;            // [128][32]  4096
  ushort* const lB0 = smem + 4096;     // [256][32]  8192
  ushort* const lA1 = smem + 12288;
  ushort* const lB1 = smem + 16384;
  ushort* const lA2 = smem + 24576;
  ushort* const lB2 = smem + 28672;

  const int tid = threadIdx.x;
  const int lane = tid & 63;
  const int wave = tid >> 6;
  const int wr = wave >> 2, wc = wave & 3;  // 2x4 waves; 64x64 out each

  // XCD swizzle (nwg = 2*512 = 1024, divisible by 8 -> bijective):
  const int lin = blockIdx.y * gridDim.x + blockIdx.x;
  const int nwg = gridDim.x * gridDim.y;
  const int wg = (lin & 7) * (nwg >> 3) + (lin >> 3);
  const int n0 = (wg & 1) * TBN;
  const size_t m0 = (size_t)(wg >> 1) * TBM;

  // staging: thread tid -> linear LDS 16B slot tid (A) / {tid, 512+tid} (B);
  // source row = slot>>2, source chunk = (slot&3) ^ (row&3).
  const int srow = tid >> 2;                        // 0..127
  const int schunk = ((tid & 3) ^ (srow & 3)) * 8;  // swizzled global chunk

  f32x4 acc[4][4] = {};

  // fragment-read addressing
  const int rsel = lane & 15;
  const int g = lane >> 4;
  const int ch = ((g ^ (rsel & 3))) * 8;  // swizzled chunk offset (ushorts)

#define STAGE(bufA, bufB, kt)                                                    \
  {                                                                              \
    const int k0_ = (kt) * TBK;                                                  \
    gload16(A + (m0 + srow) * D + k0_ + schunk, &(bufA)[tid * 8]);               \
    gload16(BT + (size_t)(n0 + srow) * D + k0_ + schunk, &(bufB)[tid * 8]);      \
    gload16(BT + (size_t)(n0 + 128 + srow) * D + k0_ + schunk,                   \
            &(bufB)[(512 + tid) * 8]);                                           \
  }

#define COMPUTE(bufA, bufB)                                                      \
  {                                                                              \
    __builtin_amdgcn_s_setprio(1);                                               \
    bf16x8 af_[4], bf_[4];                                                       \
    _Pragma("unroll") for (int j_ = 0; j_ < 4; ++j_)                             \
        bf_[j_] = *(const bf16x8*)&(bufB)[(wc * 64 + j_ * 16 + rsel) * TBK + ch];\
    _Pragma("unroll") for (int i_ = 0; i_ < 4; ++i_)                             \
        af_[i_] = *(const bf16x8*)&(bufA)[(wr * 64 + i_ * 16 + rsel) * TBK + ch];\
    _Pragma("unroll") for (int i_ = 0; i_ < 4; ++i_)                             \
        _Pragma("unroll") for (int j_ = 0; j_ < 4; ++j_)                         \
            acc[i_][j_] = __builtin_amdgcn_mfma_f32_16x16x32_bf16(               \
                af_[i_], bf_[j_], acc[i_][j_], 0, 0, 0);                         \
    __builtin_amdgcn_s_setprio(0);                                               \
  }

#define VMW(N)                                              \
  asm volatile("s_waitcnt vmcnt(" #N ")" ::: "memory");     \
  __builtin_amdgcn_sched_barrier(0)
#define BAR() __builtin_amdgcn_s_barrier()

  // K=512 -> 16 K-tiles; buffer b = tile%3; 2-tile-ahead.
  STAGE(lA0, lB0, 0); STAGE(lA1, lB1, 1); STAGE(lA2, lB2, 2);
  VMW(6); BAR(); COMPUTE(lA0, lB0); BAR(); STAGE(lA0, lB0, 3);   // t=0
  VMW(6); BAR(); COMPUTE(lA1, lB1); BAR(); STAGE(lA1, lB1, 4);   // t=1
  VMW(6); BAR(); COMPUTE(lA2, lB2); BAR(); STAGE(lA2, lB2, 5);   // t=2
  VMW(6); BAR(); COMPUTE(lA0, lB0); BAR(); STAGE(lA0, lB0, 6);   // t=3
  VMW(6); BAR(); COMPUTE(lA1, lB1); BAR(); STAGE(lA1, lB1, 7);   // t=4
  VMW(6); BAR(); COMPUTE(lA2, lB2); BAR(); STAGE(lA2, lB2, 8);   // t=5
  VMW(6); BAR(); COMPUTE(lA0, lB0); BAR(); STAGE(lA0, lB0, 9);   // t=6
  VMW(6); BAR(); COMPUTE(lA1, lB1); BAR(); STAGE(lA1, lB1, 10);  // t=7
  VMW(6); BAR(); COMPUTE(lA2, lB2); BAR(); STAGE(lA2, lB2, 11);  // t=8
  VMW(6); BAR(); COMPUTE(lA0, lB0); BAR(); STAGE(lA0, lB0, 12);  // t=9
  VMW(6); BAR(); COMPUTE(lA1, lB1); BAR(); STAGE(lA1, lB1, 13);  // t=10
  VMW(6); BAR(); COMPUTE(lA2, lB2); BAR(); STAGE(lA2, lB2, 14);  // t=11
  VMW(6); BAR(); COMPUTE(lA0, lB0); BAR(); STAGE(lA0, lB0, 15);  // t=12
  VMW(6); BAR(); COMPUTE(lA1, lB1); BAR();                       // t=13
  VMW(3); BAR(); COMPUTE(lA2, lB2); BAR();                       // t=14
  VMW(0); BAR(); COMPUTE(lA0, lB0);                              // t=15
#undef STAGE
#undef COMPUTE
#undef VMW

  __syncthreads();  // drain before epilogue reuses smem

  // ---- epilogue via two 32 KB LDS half-tiles [64][256] bf16 ----
  // C/D layout: col=lane&15, row=(lane>>4)*4+reg (m89-verified)
  const int rbase = g * 4;
#pragma unroll
  for (int h = 0; h < 2; ++h) {
    if (wr == h) {
#pragma unroll
      for (int j = 0; j < 4; ++j) {
        const int col = wc * 64 + j * 16 + rsel;
        const float bv = bias[n0 + col];
#pragma unroll
        for (int i = 0; i < 4; ++i) {
#pragma unroll
          for (int q = 0; q < 4; ++q) {
            const int lrow = i * 16 + rbase + q;  // 0..63
            float v = acc[i][j][q] + bv;
            v = (v > 0.f) ? v : 0.01f * v;
            smem[lrow * TBN + col] = f2b(v);
          }
        }
      }
    }
    __syncthreads();
    // cooperative store: 64 rows x 512B contiguous
#pragma unroll
    for (int it = 0; it < 4; ++it) {
      const int slot = it * 512 + tid;  // 2048 slots
      const int row = slot >> 5;
      const int chunk = slot & 31;
      const uint4 vv = *(const uint4*)&smem[row * TBN + chunk * 8];
      const size_t grow = m0 + h * 64 + row;
      *(uint4*)(Obf + grow * D + n0 + chunk * 8) = vv;
      if (Of32) {
        float4 f0, f1;
        f0.x = b_lo(vv.x); f0.y = b_hi(vv.x); f0.z = b_lo(vv.y); f0.w = b_hi(vv.y);
        f1.x = b_lo(vv.z); f1.y = b_hi(vv.z); f1.z = b_lo(vv.w); f1.w = b_hi(vv.w);
        float* op = Of32 + grow * D + n0 + chunk * 8;
        *(float4*)op = f0;
        *(float4*)(op + 4) = f1;
      }
    }
    // fused segment-max over this half-tile (still resident in LDS)
    if (mvstage) {
      const int col = tid & 255;          // 0..255 within n0 slice
      const int rh = tid >> 8;            // 0/1: rows rh*32..rh*32+31
      const size_t rowbase = m0 + h * 64 + rh * 32;
      float mx = -3.4e38f;
      int curg = batch[rowbase];
#pragma unroll 4
      for (int r = 0; r < 32; ++r) {
        const int gg = batch[rowbase + r];
        if (gg != curg) {
          atomicMax(&mvstage[(size_t)curg * D + n0 + col], encf(mx));
          mx = -3.4e38f;
          curg = gg;
        }
        mx = fmaxf(mx, b_lo((uint)smem[(rh * 32 + r) * TBN + col]));
      }
      atomicMax(&mvstage[(size_t)curg * D + n0 + col], encf(mx));
    }
    __syncthreads();
  }
}

// ------------- pool projection, split-K (R10-verified); mv is ENCODED ------
__global__ __launch_bounds__(256) void pool_partial(
    const uint* __restrict__ mv, const float* __restrict__ proj_w,
    const float* __restrict__ pool_w, float* __restrict__ pp) {
  const int g = blockIdx.x;                      // 64
  const int o = blockIdx.y * 256 + threadIdx.x;  // 2 x 256
  const int s = blockIdx.z >> 2, kq = blockIdx.z & 3;
  const float* W = (s == 0) ? proj_w : pool_w + (size_t)(s - 1) * D * D;
  const uint* m = mv + ((size_t)s * 64 + g) * D + kq * 128;
  const float* Wp = W + (size_t)(kq * 128) * D + o;
  float acc = 0.f;
#pragma unroll 8
  for (int k = 0; k < 128; ++k) acc = fmaf(decf(m[k]), Wp[(size_t)k * D], acc);
  pp[((size_t)blockIdx.z * 64 + g) * D + o] = acc;
}

__global__ __launch_bounds__(256) void pool_reduce(
    const float* __restrict__ pp, const float* __restrict__ proj_b,
    const float* __restrict__ pool_b, float* __restrict__ part) {
  const int i = blockIdx.x * 256 + threadIdx.x;  // < 64*512
  const int g = i >> 9, o = i & (D - 1);
  float acc = proj_b[o] + pool_b[o] + pool_b[D + o] + pool_b[2 * D + o];
#pragma unroll
  for (int s = 0; s < 16; ++s) acc += pp[((size_t)s * 64 + g) * D + o];
  part[i] = acc;
}

// ---------------------------------------------------------------------------
extern "C" void kernel_launch(void* const* d_in, const int* in_sizes, int n_in,
                              void* d_out, int out_size, void* d_ws, size_t ws_size,
                              hipStream_t stream) {
  const float* x = (const float*)d_in[0];
  const int* ei = (const int*)d_in[1];
  const int* batch = (const int*)d_in[2];
  const float* proj_w = (const float*)d_in[3];
  const float* proj_b = (const float*)d_in[4];
  const float* lin1_w = (const float*)d_in[5];
  const float* lin1_b = (const float*)d_in[6];
  const float* lin2_w = (const float*)d_in[7];
  const float* lin2_b = (const float*)d_in[8];
  const float* eps = (const float*)d_in[9];
  const float* pool_w = (const float*)d_in[10];
  const float* pool_b = (const float*)d_in[11];

  const int N = in_sizes[0] / D;  // 65536
  const int E = in_sizes[1] / 2;  // 524288
  const int B = 64;
  const int* src = ei;
  const int* dst = ei + E;

  float* part = (float*)d_out;         // [64][512]
  float* xout = part + (size_t)B * D;  // [N][512]

  // workspace carve (~212 MB)
  char* w = (char*)d_ws;
  ushort* xb = (ushort*)w;   w += (size_t)N * D * 2;
  ushort* hb = (ushort*)w;   w += (size_t)N * D * 2;
  ushort* tb = (ushort*)w;   w += (size_t)N * D * 2;
  ushort* l1bt = (ushort*)w; w += (size_t)3 * D * D * 2;
  ushort* l2bt = (ushort*)w; w += (size_t)3 * D * D * 2;
  int* rowptr = (int*)w;     w += (size_t)(N + 4) * 4;
  int* cursor = (int*)w;     w += (size_t)N * 4;
  int* deg = (int*)w;        w += (size_t)N * 4;
  int* csr = (int*)w;        w += (size_t)E * 4;
  int* bsum = (int*)w;       w += 256 * 4;
  int* gstart = (int*)w;     w += 128 * 4;
  uint* mvall = (uint*)w;     w += (size_t)4 * B * D * 4;   // [4][64][512] encoded
  float* pp = (float*)w;      w += (size_t)16 * B * D * 4;  // [16][64][512]
  (void)ws_size; (void)n_in; (void)out_size; (void)gstart;

  (void)hipMemsetAsync(deg, 0, (size_t)N * 4, stream);
  (void)hipMemsetAsync(mvall, 0, (size_t)4 * B * D * 4, stream);
  // convert + fused stage-0 segmax
  f32_to_bf16_segmax<<<N / 128, 256, 0, stream>>>(x, xb, batch, mvall);
  transpose_all<<<dim3(8, 8, 6), 256, 0, stream>>>(lin1_w, lin2_w, l1bt, l2bt);
  count_deg<<<(E + 255) / 256, 256, 0, stream>>>(dst, deg, E);
  scan_block<<<N / 256, 256, 0, stream>>>(deg, rowptr, bsum);
  scan_block<<<1, 256, 0, stream>>>(bsum, bsum, (int*)nullptr);
  scan_fixup<<<N / 256, 256, 0, stream>>>(rowptr, bsum, cursor, N, E);
  fill_csr<<<(E + 255) / 256, 256, 0, stream>>>(src, dst, cursor, csr, E);

  for (int l = 0; l < 3; ++l) {
    agg_kernel<<<N / 4, 256, 0, stream>>>(xb, rowptr, csr, eps, l, hb);
    gemm_bias_leaky<<<dim3(D / TBN, N / TBM), 512, 0, stream>>>(
        hb, l1bt + (size_t)l * D * D, lin1_b + (size_t)l * D, tb, nullptr,
        batch, nullptr);
    gemm_bias_leaky<<<dim3(D / TBN, N / TBM), 512, 0, stream>>>(
        tb, l2bt + (size_t)l * D * D, lin2_b + (size_t)l * D, xb,
        (l == 2) ? xout : nullptr, batch,
        mvall + (size_t)(l + 1) * B * D);  // fused segmax stage l+1
  }

  // split-K pool projection (decodes mvall)
  pool_partial<<<dim3(B, 2, 16), 256, 0, stream>>>(mvall, proj_w, pool_w, pp);
  pool_reduce<<<B * D / 256, 256, 0, stream>>>(pp, proj_b, pool_b, part);
}

// Round 14
// 735.586 us; speedup vs baseline: 1.3179x; 1.0108x over previous
//
#include <hip/hip_runtime.h>

typedef unsigned int uint;
typedef unsigned short ushort;

#define D 512
#define TBM 128   // M-tile
#define TBN 256   // N-tile
#define TBK 32    // K-step
#define CPAD 264  // padded C-tile row (ushorts): 528B stride halves epilogue bank conflicts

typedef __attribute__((ext_vector_type(8))) short bf16x8;
typedef __attribute__((ext_vector_type(4))) float f32x4;

__device__ __forceinline__ ushort f2b(float f) {
  uint u = __builtin_bit_cast(uint, f);
  return (ushort)((u + 0x7FFFu + ((u >> 16) & 1u)) >> 16);  // RNE
}
__device__ __forceinline__ float b_lo(uint u) { return __builtin_bit_cast(float, u << 16); }
__device__ __forceinline__ float b_hi(uint u) { return __builtin_bit_cast(float, u & 0xFFFF0000u); }

// monotone float<->uint map: uint order == float order (for max via atomicMax)
__device__ __forceinline__ uint encf(float x) {
  uint u = __builtin_bit_cast(uint, x);
  return ((int)u >= 0) ? (u | 0x80000000u) : ~u;
}
__device__ __forceinline__ float decf(uint u) {
  return (u & 0x80000000u) ? __builtin_bit_cast(float, u ^ 0x80000000u)
                           : __builtin_bit_cast(float, ~u);
}

__device__ __forceinline__ void gload16(const void* g, void* l) {
  __builtin_amdgcn_global_load_lds((const __attribute__((address_space(1))) void*)g,
                                   (__attribute__((address_space(3))) void*)l, 16, 0, 0);
}

// ---- f32 -> bf16 convert + FUSED stage-0 segment-max (R13-verified) -------
__global__ __launch_bounds__(256) void f32_to_bf16_segmax(
    const float* __restrict__ in, ushort* __restrict__ out,
    const int* __restrict__ batch, uint* __restrict__ mv0) {
  const int t = threadIdx.x;
  const int chunk = t & 63;
  const int rsub = t >> 6;
  const int row0 = blockIdx.x * 128;
  float mx[8];
#pragma unroll
  for (int j = 0; j < 8; ++j) mx[j] = -3.4e38f;
  int curg = batch[row0 + rsub];
#pragma unroll 4
  for (int k = 0; k < 32; ++k) {
    const int row = row0 + rsub + k * 4;
    const int gg = batch[row];
    if (gg != curg) {
#pragma unroll
      for (int j = 0; j < 8; ++j)
        atomicMax(&mv0[(size_t)curg * D + chunk * 8 + j], encf(mx[j]));
#pragma unroll
      for (int j = 0; j < 8; ++j) mx[j] = -3.4e38f;
      curg = gg;
    }
    const float4* p = (const float4*)(in + (size_t)row * D + chunk * 8);
    const float4 a = p[0], b = p[1];
    float v[8] = {a.x, a.y, a.z, a.w, b.x, b.y, b.z, b.w};
    uint4 o;
    o.x = f2b(v[0]) | ((uint)f2b(v[1]) << 16);
    o.y = f2b(v[2]) | ((uint)f2b(v[3]) << 16);
    o.z = f2b(v[4]) | ((uint)f2b(v[5]) << 16);
    o.w = f2b(v[6]) | ((uint)f2b(v[7]) << 16);
    *(uint4*)(out + (size_t)row * D + chunk * 8) = o;
#pragma unroll
    for (int j = 0; j < 8; ++j) mx[j] = fmaxf(mx[j], v[j]);
  }
#pragma unroll
  for (int j = 0; j < 8; ++j)
    atomicMax(&mv0[(size_t)curg * D + chunk * 8 + j], encf(mx[j]));
}

// ---- transpose all 6 weight mats: 512x512 f32 [k][o] -> bf16 BT [o][k] ----
__global__ __launch_bounds__(256) void transpose_all(const float* __restrict__ lin1_w,
                                                     const float* __restrict__ lin2_w,
                                                     ushort* __restrict__ l1bt,
                                                     ushort* __restrict__ l2bt) {
  __shared__ float tile[64][65];
  const int z = blockIdx.z, l = z >> 1;
  const float* W = ((z & 1) ? lin2_w : lin1_w) + (size_t)l * D * D;
  ushort* BT = ((z & 1) ? l2bt : l1bt) + (size_t)l * D * D;
  const int bk = blockIdx.x * 64;  // k block
  const int bo = blockIdx.y * 64;  // o block
  const int tx = threadIdx.x & 63, ty = threadIdx.x >> 6;
#pragma unroll
  for (int r = 0; r < 64; r += 4)
    tile[r + ty][tx] = W[(size_t)(bk + r + ty) * D + bo + tx];
  __syncthreads();
#pragma unroll
  for (int r = 0; r < 64; r += 4)
    BT[(size_t)(bo + r + ty) * D + bk + tx] = f2b(tile[tx][r + ty]);
}

// ---------------------------- CSR build ------------------------------------
__global__ void count_deg(const int* __restrict__ dst, int* __restrict__ deg, int E) {
  const int e = blockIdx.x * 256 + threadIdx.x;
  if (e < E) atomicAdd(&deg[dst[e]], 1);
}

__global__ __launch_bounds__(256) void scan_block(const int* __restrict__ in,
                                                  int* __restrict__ out,
                                                  int* __restrict__ bsum) {
  __shared__ int sm[256];
  const int t = threadIdx.x;
  const int gi = blockIdx.x * 256 + t;
  const int v = in[gi];
  int x = v;
  sm[t] = x;
  __syncthreads();
#pragma unroll
  for (int off = 1; off < 256; off <<= 1) {
    const int y = (t >= off) ? sm[t - off] : 0;
    __syncthreads();
    x += y;
    sm[t] = x;
    __syncthreads();
  }
  out[gi] = x - v;  // exclusive
  if (t == 255 && bsum) bsum[blockIdx.x] = x;
}

__global__ void scan_fixup(int* __restrict__ rowptr, const int* __restrict__ bsum,
                           int* __restrict__ cursor, int N, int E) {
  const int i = blockIdx.x * 256 + threadIdx.x;
  const int r = rowptr[i] + bsum[i >> 8];
  rowptr[i] = r;
  cursor[i] = r;
  if (i == 0) rowptr[N] = E;
}

__global__ void fill_csr(const int* __restrict__ src, const int* __restrict__ dst,
                         int* __restrict__ cursor, int* __restrict__ csr, int E) {
  const int e = blockIdx.x * 256 + threadIdx.x;
  if (e >= E) return;
  const int pos = atomicAdd(&cursor[dst[e]], 1);
  csr[pos] = src[e];
}

// --------------- GIN aggregation: h = (1+eps)*x + sum_nbr x ----------------
// At its random-gather structural floor (R2/R4/R7 evidence). Do not touch.
#define ACC8(v)                                          \
  a[0] += b_lo((v).x); a[1] += b_hi((v).x);              \
  a[2] += b_lo((v).y); a[3] += b_hi((v).y);              \
  a[4] += b_lo((v).z); a[5] += b_hi((v).z);              \
  a[6] += b_lo((v).w); a[7] += b_hi((v).w)

__global__ __launch_bounds__(256) void agg_kernel(const ushort* __restrict__ xb,
                                                  const int* __restrict__ rowptr,
                                                  const int* __restrict__ csr,
                                                  const float* __restrict__ eps_arr,
                                                  int layer, ushort* __restrict__ h) {
  const int node = blockIdx.x * 4 + (threadIdx.x >> 6);
  const int lane = threadIdx.x & 63;
  const float sc = 1.0f + eps_arr[layer];
  const size_t off = (size_t)lane * 8;
  const size_t base = (size_t)node * D + off;
  const uint4 u = *(const uint4*)(xb + base);
  float a[8];
  a[0] = b_lo(u.x) * sc; a[1] = b_hi(u.x) * sc;
  a[2] = b_lo(u.y) * sc; a[3] = b_hi(u.y) * sc;
  a[4] = b_lo(u.z) * sc; a[5] = b_hi(u.z) * sc;
  a[6] = b_lo(u.w) * sc; a[7] = b_hi(u.w) * sc;
  int e = rowptr[node];
  const int en = rowptr[node + 1];
  for (; e + 4 <= en; e += 4) {
    const int s0 = csr[e], s1 = csr[e + 1], s2 = csr[e + 2], s3 = csr[e + 3];
    const uint4 v0 = *(const uint4*)(xb + (size_t)s0 * D + off);
    const uint4 v1 = *(const uint4*)(xb + (size_t)s1 * D + off);
    const uint4 v2 = *(const uint4*)(xb + (size_t)s2 * D + off);
    const uint4 v3 = *(const uint4*)(xb + (size_t)s3 * D + off);
    ACC8(v0); ACC8(v1); ACC8(v2); ACC8(v3);
  }
  if (e + 2 <= en) {
    const int s0 = csr[e], s1 = csr[e + 1];
    const uint4 v0 = *(const uint4*)(xb + (size_t)s0 * D + off);
    const uint4 v1 = *(const uint4*)(xb + (size_t)s1 * D + off);
    ACC8(v0); ACC8(v1);
    e += 2;
  }
  if (e < en) {
    const uint4 v0 = *(const uint4*)(xb + (size_t)csr[e] * D + off);
    ACC8(v0);
  }
  uint4 o;
  o.x = f2b(a[0]) | ((uint)f2b(a[1]) << 16);
  o.y = f2b(a[2]) | ((uint)f2b(a[3]) << 16);
  o.z = f2b(a[4]) | ((uint)f2b(a[5]) << 16);
  o.w = f2b(a[6]) | ((uint)f2b(a[7]) << 16);
  *(uint4*)(h + base) = o;
}

// ------ bf16 GEMM: O = leaky(A @ BT^T + bias), 128x256 tile, BK=32 ---------
// R13 base: 2 blocks/CU, 3-buffer 2-ahead counted vmcnt, chunk-XOR swizzle,
// fused segmax. R14: (a) Obf nullable — last-layer GEMM2 skips the dead 67MB
// bf16 write (WRITE was 205MB there); (b) C-tile padded to CPAD=264 ushorts
// (528B row stride -> epilogue scalar writes drop 8-way -> 4-way conflicts;
// row stays 16B-aligned for b128 cooperative reads).
__global__ __launch_bounds__(512, 4) void gemm_bias_leaky(
    const ushort* __restrict__ A, const ushort* __restrict__ BT,
    const float* __restrict__ bias, ushort* __restrict__ Obf,
    float* __restrict__ Of32, const int* __restrict__ batch,
    uint* __restrict__ mvstage) {
  __shared__ alignas(16) ushort smem[36864];  // 72 KB
  ushort* const lA0 = smem;            // [128][32]  4096
  ushort* const lB0 = smem + 4096;     // [256][32]  8192
  ushort* const lA1 = smem + 12288;
  ushort* const lB1 = smem + 16384;
  ushort* const lA2 = smem + 24576;
  ushort* const lB2 = smem + 28672;

  const int tid = threadIdx.x;
  const int lane = tid & 63;
  const int wave = tid >> 6;
  const int wr = wave >> 2, wc = wave & 3;  // 2x4 waves; 64x64 out each

  // XCD swizzle (nwg = 2*512 = 1024, divisible by 8 -> bijective):
  const int lin = blockIdx.y * gridDim.x + blockIdx.x;
  const int nwg = gridDim.x * gridDim.y;
  const int wg = (lin & 7) * (nwg >> 3) + (lin >> 3);
  const int n0 = (wg & 1) * TBN;
  const size_t m0 = (size_t)(wg >> 1) * TBM;

  // staging: thread tid -> linear LDS 16B slot tid (A) / {tid, 512+tid} (B);
  // source row = slot>>2, source chunk = (slot&3) ^ (row&3).
  const int srow = tid >> 2;                        // 0..127
  const int schunk = ((tid & 3) ^ (srow & 3)) * 8;  // swizzled global chunk

  f32x4 acc[4][4] = {};

  // fragment-read addressing
  const int rsel = lane & 15;
  const int g = lane >> 4;
  const int ch = ((g ^ (rsel & 3))) * 8;  // swizzled chunk offset (ushorts)

#define STAGE(bufA, bufB, kt)                                                    \
  {                                                                              \
    const int k0_ = (kt) * TBK;                                                  \
    gload16(A + (m0 + srow) * D + k0_ + schunk, &(bufA)[tid * 8]);               \
    gload16(BT + (size_t)(n0 + srow) * D + k0_ + schunk, &(bufB)[tid * 8]);      \
    gload16(BT + (size_t)(n0 + 128 + srow) * D + k0_ + schunk,                   \
            &(bufB)[(512 + tid) * 8]);                                           \
  }

#define COMPUTE(bufA, bufB)                                                      \
  {                                                                              \
    __builtin_amdgcn_s_setprio(1);                                               \
    bf16x8 af_[4], bf_[4];                                                       \
    _Pragma("unroll") for (int j_ = 0; j_ < 4; ++j_)                             \
        bf_[j_] = *(const bf16x8*)&(bufB)[(wc * 64 + j_ * 16 + rsel) * TBK + ch];\
    _Pragma("unroll") for (int i_ = 0; i_ < 4; ++i_)                             \
        af_[i_] = *(const bf16x8*)&(bufA)[(wr * 64 + i_ * 16 + rsel) * TBK + ch];\
    _Pragma("unroll") for (int i_ = 0; i_ < 4; ++i_)                             \
        _Pragma("unroll") for (int j_ = 0; j_ < 4; ++j_)                         \
            acc[i_][j_] = __builtin_amdgcn_mfma_f32_16x16x32_bf16(               \
                af_[i_], bf_[j_], acc[i_][j_], 0, 0, 0);                         \
    __builtin_amdgcn_s_setprio(0);                                               \
  }

#define VMW(N)                                              \
  asm volatile("s_waitcnt vmcnt(" #N ")" ::: "memory");     \
  __builtin_amdgcn_sched_barrier(0)
#define BAR() __builtin_amdgcn_s_barrier()

  // K=512 -> 16 K-tiles; buffer b = tile%3; 2-tile-ahead.
  STAGE(lA0, lB0, 0); STAGE(lA1, lB1, 1); STAGE(lA2, lB2, 2);
  VMW(6); BAR(); COMPUTE(lA0, lB0); BAR(); STAGE(lA0, lB0, 3);   // t=0
  VMW(6); BAR(); COMPUTE(lA1, lB1); BAR(); STAGE(lA1, lB1, 4);   // t=1
  VMW(6); BAR(); COMPUTE(lA2, lB2); BAR(); STAGE(lA2, lB2, 5);   // t=2
  VMW(6); BAR(); COMPUTE(lA0, lB0); BAR(); STAGE(lA0, lB0, 6);   // t=3
  VMW(6); BAR(); COMPUTE(lA1, lB1); BAR(); STAGE(lA1, lB1, 7);   // t=4
  VMW(6); BAR(); COMPUTE(lA2, lB2); BAR(); STAGE(lA2, lB2, 8);   // t=5
  VMW(6); BAR(); COMPUTE(lA0, lB0); BAR(); STAGE(lA0, lB0, 9);   // t=6
  VMW(6); BAR(); COMPUTE(lA1, lB1); BAR(); STAGE(lA1, lB1, 10);  // t=7
  VMW(6); BAR(); COMPUTE(lA2, lB2); BAR(); STAGE(lA2, lB2, 11);  // t=8
  VMW(6); BAR(); COMPUTE(lA0, lB0); BAR(); STAGE(lA0, lB0, 12);  // t=9
  VMW(6); BAR(); COMPUTE(lA1, lB1); BAR(); STAGE(lA1, lB1, 13);  // t=10
  VMW(6); BAR(); COMPUTE(lA2, lB2); BAR(); STAGE(lA2, lB2, 14);  // t=11
  VMW(6); BAR(); COMPUTE(lA0, lB0); BAR(); STAGE(lA0, lB0, 15);  // t=12
  VMW(6); BAR(); COMPUTE(lA1, lB1); BAR();                       // t=13
  VMW(3); BAR(); COMPUTE(lA2, lB2); BAR();                       // t=14
  VMW(0); BAR(); COMPUTE(lA0, lB0);                              // t=15
#undef STAGE
#undef COMPUTE
#undef VMW

  __syncthreads();  // drain before epilogue reuses smem

  // ---- epilogue via two LDS half-tiles [64][CPAD] bf16 (33.8 KB) ----
  // C/D layout: col=lane&15, row=(lane>>4)*4+reg (m89-verified)
  const int rbase = g * 4;
#pragma unroll
  for (int h = 0; h < 2; ++h) {
    if (wr == h) {
#pragma unroll
      for (int j = 0; j < 4; ++j) {
        const int col = wc * 64 + j * 16 + rsel;
        const float bv = bias[n0 + col];
#pragma unroll
        for (int i = 0; i < 4; ++i) {
#pragma unroll
          for (int q = 0; q < 4; ++q) {
            const int lrow = i * 16 + rbase + q;  // 0..63
            float v = acc[i][j][q] + bv;
            v = (v > 0.f) ? v : 0.01f * v;
            smem[lrow * CPAD + col] = f2b(v);
          }
        }
      }
    }
    __syncthreads();
    // cooperative store: 64 rows x 512B contiguous
#pragma unroll
    for (int it = 0; it < 4; ++it) {
      const int slot = it * 512 + tid;  // 2048 slots
      const int row = slot >> 5;
      const int chunk = slot & 31;
      const uint4 vv = *(const uint4*)&smem[row * CPAD + chunk * 8];
      const size_t grow = m0 + h * 64 + row;
      if (Obf) *(uint4*)(Obf + grow * D + n0 + chunk * 8) = vv;
      if (Of32) {
        float4 f0, f1;
        f0.x = b_lo(vv.x); f0.y = b_hi(vv.x); f0.z = b_lo(vv.y); f0.w = b_hi(vv.y);
        f1.x = b_lo(vv.z); f1.y = b_hi(vv.z); f1.z = b_lo(vv.w); f1.w = b_hi(vv.w);
        float* op = Of32 + grow * D + n0 + chunk * 8;
        *(float4*)op = f0;
        *(float4*)(op + 4) = f1;
      }
    }
    // fused segment-max over this half-tile (still resident in LDS)
    if (mvstage) {
      const int col = tid & 255;          // 0..255 within n0 slice
      const int rh = tid >> 8;            // 0/1: rows rh*32..rh*32+31
      const size_t rowbase = m0 + h * 64 + rh * 32;
      float mx = -3.4e38f;
      int curg = batch[rowbase];
#pragma unroll 4
      for (int r = 0; r < 32; ++r) {
        const int gg = batch[rowbase + r];
        if (gg != curg) {
          atomicMax(&mvstage[(size_t)curg * D + n0 + col], encf(mx));
          mx = -3.4e38f;
          curg = gg;
        }
        mx = fmaxf(mx, b_lo((uint)smem[(rh * 32 + r) * CPAD + col]));
      }
      atomicMax(&mvstage[(size_t)curg * D + n0 + col], encf(mx));
    }
    __syncthreads();
  }
}

// ------------- pool projection, split-K (R10-verified); mv is ENCODED ------
__global__ __launch_bounds__(256) void pool_partial(
    const uint* __restrict__ mv, const float* __restrict__ proj_w,
    const float* __restrict__ pool_w, float* __restrict__ pp) {
  const int g = blockIdx.x;                      // 64
  const int o = blockIdx.y * 256 + threadIdx.x;  // 2 x 256
  const int s = blockIdx.z >> 2, kq = blockIdx.z & 3;
  const float* W = (s == 0) ? proj_w : pool_w + (size_t)(s - 1) * D * D;
  const uint* m = mv + ((size_t)s * 64 + g) * D + kq * 128;
  const float* Wp = W + (size_t)(kq * 128) * D + o;
  float acc = 0.f;
#pragma unroll 8
  for (int k = 0; k < 128; ++k) acc = fmaf(decf(m[k]), Wp[(size_t)k * D], acc);
  pp[((size_t)blockIdx.z * 64 + g) * D + o] = acc;
}

__global__ __launch_bounds__(256) void pool_reduce(
    const float* __restrict__ pp, const float* __restrict__ proj_b,
    const float* __restrict__ pool_b, float* __restrict__ part) {
  const int i = blockIdx.x * 256 + threadIdx.x;  // < 64*512
  const int g = i >> 9, o = i & (D - 1);
  float acc = proj_b[o] + pool_b[o] + pool_b[D + o] + pool_b[2 * D + o];
#pragma unroll
  for (int s = 0; s < 16; ++s) acc += pp[((size_t)s * 64 + g) * D + o];
  part[i] = acc;
}

// ---------------------------------------------------------------------------
extern "C" void kernel_launch(void* const* d_in, const int* in_sizes, int n_in,
                              void* d_out, int out_size, void* d_ws, size_t ws_size,
                              hipStream_t stream) {
  const float* x = (const float*)d_in[0];
  const int* ei = (const int*)d_in[1];
  const int* batch = (const int*)d_in[2];
  const float* proj_w = (const float*)d_in[3];
  const float* proj_b = (const float*)d_in[4];
  const float* lin1_w = (const float*)d_in[5];
  const float* lin1_b = (const float*)d_in[6];
  const float* lin2_w = (const float*)d_in[7];
  const float* lin2_b = (const float*)d_in[8];
  const float* eps = (const float*)d_in[9];
  const float* pool_w = (const float*)d_in[10];
  const float* pool_b = (const float*)d_in[11];

  const int N = in_sizes[0] / D;  // 65536
  const int E = in_sizes[1] / 2;  // 524288
  const int B = 64;
  const int* src = ei;
  const int* dst = ei + E;

  float* part = (float*)d_out;         // [64][512]
  float* xout = part + (size_t)B * D;  // [N][512]

  // workspace carve (~212 MB)
  char* w = (char*)d_ws;
  ushort* xb = (ushort*)w;   w += (size_t)N * D * 2;
  ushort* hb = (ushort*)w;   w += (size_t)N * D * 2;
  ushort* tb = (ushort*)w;   w += (size_t)N * D * 2;
  ushort* l1bt = (ushort*)w; w += (size_t)3 * D * D * 2;
  ushort* l2bt = (ushort*)w; w += (size_t)3 * D * D * 2;
  int* rowptr = (int*)w;     w += (size_t)(N + 4) * 4;
  int* cursor = (int*)w;     w += (size_t)N * 4;
  int* deg = (int*)w;        w += (size_t)N * 4;
  int* csr = (int*)w;        w += (size_t)E * 4;
  int* bsum = (int*)w;       w += 256 * 4;
  int* gstart = (int*)w;     w += 128 * 4;
  uint* mvall = (uint*)w;     w += (size_t)4 * B * D * 4;   // [4][64][512] encoded
  float* pp = (float*)w;      w += (size_t)16 * B * D * 4;  // [16][64][512]
  (void)ws_size; (void)n_in; (void)out_size; (void)gstart;

  (void)hipMemsetAsync(deg, 0, (size_t)N * 4, stream);
  (void)hipMemsetAsync(mvall, 0, (size_t)4 * B * D * 4, stream);
  // convert + fused stage-0 segmax
  f32_to_bf16_segmax<<<N / 128, 256, 0, stream>>>(x, xb, batch, mvall);
  transpose_all<<<dim3(8, 8, 6), 256, 0, stream>>>(lin1_w, lin2_w, l1bt, l2bt);
  count_deg<<<(E + 255) / 256, 256, 0, stream>>>(dst, deg, E);
  scan_block<<<N / 256, 256, 0, stream>>>(deg, rowptr, bsum);
  scan_block<<<1, 256, 0, stream>>>(bsum, bsum, (int*)nullptr);
  scan_fixup<<<N / 256, 256, 0, stream>>>(rowptr, bsum, cursor, N, E);
  fill_csr<<<(E + 255) / 256, 256, 0, stream>>>(src, dst, cursor, csr, E);

  for (int l = 0; l < 3; ++l) {
    agg_kernel<<<N / 4, 256, 0, stream>>>(xb, rowptr, csr, eps, l, hb);
    gemm_bias_leaky<<<dim3(D / TBN, N / TBM), 512, 0, stream>>>(
        hb, l1bt + (size_t)l * D * D, lin1_b + (size_t)l * D, tb, nullptr,
        batch, nullptr);
    gemm_bias_leaky<<<dim3(D / TBN, N / TBM), 512, 0, stream>>>(
        tb, l2bt + (size_t)l * D * D, lin2_b + (size_t)l * D,
        (l == 2) ? nullptr : xb,            // last layer: xb is dead, skip 67MB write
        (l == 2) ? xout : nullptr, batch,
        mvall + (size_t)(l + 1) * B * D);   // fused segmax stage l+1
  }

  // split-K pool projection (decodes mvall)
  pool_partial<<<dim3(B, 2, 16), 256, 0, stream>>>(mvall, proj_w, pool_w, pp);
  pool_reduce<<<B * D / 256, 256, 0, stream>>>(pp, proj_b, pool_b, part);
}

// Round 15
// 727.225 us; speedup vs baseline: 1.3331x; 1.0115x over previous
//
#include <hip/hip_runtime.h>

typedef unsigned int uint;
typedef unsigned short ushort;

#define D 512
#define TBM 128   // M-tile
#define TBN 256   // N-tile
#define TBK 32    // K-step
#define CPAD 264  // padded C-tile row (ushorts): 528B stride halves epilogue bank conflicts

typedef __attribute__((ext_vector_type(8))) short bf16x8;
typedef __attribute__((ext_vector_type(4))) float f32x4;

__device__ __forceinline__ ushort f2b(float f) {
  uint u = __builtin_bit_cast(uint, f);
  return (ushort)((u + 0x7FFFu + ((u >> 16) & 1u)) >> 16);  // RNE
}
__device__ __forceinline__ float b_lo(uint u) { return __builtin_bit_cast(float, u << 16); }
__device__ __forceinline__ float b_hi(uint u) { return __builtin_bit_cast(float, u & 0xFFFF0000u); }

// monotone float<->uint map: uint order == float order (for max via atomicMax)
__device__ __forceinline__ uint encf(float x) {
  uint u = __builtin_bit_cast(uint, x);
  return ((int)u >= 0) ? (u | 0x80000000u) : ~u;
}
__device__ __forceinline__ float decf(uint u) {
  return (u & 0x80000000u) ? __builtin_bit_cast(float, u ^ 0x80000000u)
                           : __builtin_bit_cast(float, ~u);
}

__device__ __forceinline__ void gload16(const void* g, void* l) {
  __builtin_amdgcn_global_load_lds((const __attribute__((address_space(1))) void*)g,
                                   (__attribute__((address_space(3))) void*)l, 16, 0, 0);
}

// ---- f32 -> bf16 convert + FUSED stage-0 segment-max (R13-verified) -------
__global__ __launch_bounds__(256) void f32_to_bf16_segmax(
    const float* __restrict__ in, ushort* __restrict__ out,
    const int* __restrict__ batch, uint* __restrict__ mv0) {
  const int t = threadIdx.x;
  const int chunk = t & 63;
  const int rsub = t >> 6;
  const int row0 = blockIdx.x * 128;
  float mx[8];
#pragma unroll
  for (int j = 0; j < 8; ++j) mx[j] = -3.4e38f;
  int curg = batch[row0 + rsub];
#pragma unroll 4
  for (int k = 0; k < 32; ++k) {
    const int row = row0 + rsub + k * 4;
    const int gg = batch[row];
    if (gg != curg) {
#pragma unroll
      for (int j = 0; j < 8; ++j)
        atomicMax(&mv0[(size_t)curg * D + chunk * 8 + j], encf(mx[j]));
#pragma unroll
      for (int j = 0; j < 8; ++j) mx[j] = -3.4e38f;
      curg = gg;
    }
    const float4* p = (const float4*)(in + (size_t)row * D + chunk * 8);
    const float4 a = p[0], b = p[1];
    float v[8] = {a.x, a.y, a.z, a.w, b.x, b.y, b.z, b.w};
    uint4 o;
    o.x = f2b(v[0]) | ((uint)f2b(v[1]) << 16);
    o.y = f2b(v[2]) | ((uint)f2b(v[3]) << 16);
    o.z = f2b(v[4]) | ((uint)f2b(v[5]) << 16);
    o.w = f2b(v[6]) | ((uint)f2b(v[7]) << 16);
    *(uint4*)(out + (size_t)row * D + chunk * 8) = o;
#pragma unroll
    for (int j = 0; j < 8; ++j) mx[j] = fmaxf(mx[j], v[j]);
  }
#pragma unroll
  for (int j = 0; j < 8; ++j)
    atomicMax(&mv0[(size_t)curg * D + chunk * 8 + j], encf(mx[j]));
}

// ---- transpose all 6 weight mats: 512x512 f32 [k][o] -> bf16 BT [o][k] ----
__global__ __launch_bounds__(256) void transpose_all(const float* __restrict__ lin1_w,
                                                     const float* __restrict__ lin2_w,
                                                     ushort* __restrict__ l1bt,
                                                     ushort* __restrict__ l2bt) {
  __shared__ float tile[64][65];
  const int z = blockIdx.z, l = z >> 1;
  const float* W = ((z & 1) ? lin2_w : lin1_w) + (size_t)l * D * D;
  ushort* BT = ((z & 1) ? l2bt : l1bt) + (size_t)l * D * D;
  const int bk = blockIdx.x * 64;  // k block
  const int bo = blockIdx.y * 64;  // o block
  const int tx = threadIdx.x & 63, ty = threadIdx.x >> 6;
#pragma unroll
  for (int r = 0; r < 64; r += 4)
    tile[r + ty][tx] = W[(size_t)(bk + r + ty) * D + bo + tx];
  __syncthreads();
#pragma unroll
  for (int r = 0; r < 64; r += 4)
    BT[(size_t)(bo + r + ty) * D + bk + tx] = f2b(tile[tx][r + ty]);
}

// ---------------------------- CSR build ------------------------------------
__global__ void count_deg(const int* __restrict__ dst, int* __restrict__ deg, int E) {
  const int e = blockIdx.x * 256 + threadIdx.x;
  if (e < E) atomicAdd(&deg[dst[e]], 1);
}

__global__ __launch_bounds__(256) void scan_block(const int* __restrict__ in,
                                                  int* __restrict__ out,
                                                  int* __restrict__ bsum) {
  __shared__ int sm[256];
  const int t = threadIdx.x;
  const int gi = blockIdx.x * 256 + t;
  const int v = in[gi];
  int x = v;
  sm[t] = x;
  __syncthreads();
#pragma unroll
  for (int off = 1; off < 256; off <<= 1) {
    const int y = (t >= off) ? sm[t - off] : 0;
    __syncthreads();
    x += y;
    sm[t] = x;
    __syncthreads();
  }
  out[gi] = x - v;  // exclusive
  if (t == 255 && bsum) bsum[blockIdx.x] = x;
}

__global__ void scan_fixup(int* __restrict__ rowptr, const int* __restrict__ bsum,
                           int* __restrict__ cursor, int N, int E) {
  const int i = blockIdx.x * 256 + threadIdx.x;
  const int r = rowptr[i] + bsum[i >> 8];
  rowptr[i] = r;
  cursor[i] = r;
  if (i == 0) rowptr[N] = E;
}

__global__ void fill_csr(const int* __restrict__ src, const int* __restrict__ dst,
                         int* __restrict__ cursor, int* __restrict__ csr, int E) {
  const int e = blockIdx.x * 256 + threadIdx.x;
  if (e >= E) return;
  const int pos = atomicAdd(&cursor[dst[e]], 1);
  csr[pos] = src[e];
}

// --------------- GIN aggregation: h = (1+eps)*x + sum_nbr x ----------------
// At its random-gather structural floor (R2/R4/R7 evidence). Do not touch.
#define ACC8(v)                                          \
  a[0] += b_lo((v).x); a[1] += b_hi((v).x);              \
  a[2] += b_lo((v).y); a[3] += b_hi((v).y);              \
  a[4] += b_lo((v).z); a[5] += b_hi((v).z);              \
  a[6] += b_lo((v).w); a[7] += b_hi((v).w)

__global__ __launch_bounds__(256) void agg_kernel(const ushort* __restrict__ xb,
                                                  const int* __restrict__ rowptr,
                                                  const int* __restrict__ csr,
                                                  const float* __restrict__ eps_arr,
                                                  int layer, ushort* __restrict__ h) {
  const int node = blockIdx.x * 4 + (threadIdx.x >> 6);
  const int lane = threadIdx.x & 63;
  const float sc = 1.0f + eps_arr[layer];
  const size_t off = (size_t)lane * 8;
  const size_t base = (size_t)node * D + off;
  const uint4 u = *(const uint4*)(xb + base);
  float a[8];
  a[0] = b_lo(u.x) * sc; a[1] = b_hi(u.x) * sc;
  a[2] = b_lo(u.y) * sc; a[3] = b_hi(u.y) * sc;
  a[4] = b_lo(u.z) * sc; a[5] = b_hi(u.z) * sc;
  a[6] = b_lo(u.w) * sc; a[7] = b_hi(u.w) * sc;
  int e = rowptr[node];
  const int en = rowptr[node + 1];
  for (; e + 4 <= en; e += 4) {
    const int s0 = csr[e], s1 = csr[e + 1], s2 = csr[e + 2], s3 = csr[e + 3];
    const uint4 v0 = *(const uint4*)(xb + (size_t)s0 * D + off);
    const uint4 v1 = *(const uint4*)(xb + (size_t)s1 * D + off);
    const uint4 v2 = *(const uint4*)(xb + (size_t)s2 * D + off);
    const uint4 v3 = *(const uint4*)(xb + (size_t)s3 * D + off);
    ACC8(v0); ACC8(v1); ACC8(v2); ACC8(v3);
  }
  if (e + 2 <= en) {
    const int s0 = csr[e], s1 = csr[e + 1];
    const uint4 v0 = *(const uint4*)(xb + (size_t)s0 * D + off);
    const uint4 v1 = *(const uint4*)(xb + (size_t)s1 * D + off);
    ACC8(v0); ACC8(v1);
    e += 2;
  }
  if (e < en) {
    const uint4 v0 = *(const uint4*)(xb + (size_t)csr[e] * D + off);
    ACC8(v0);
  }
  uint4 o;
  o.x = f2b(a[0]) | ((uint)f2b(a[1]) << 16);
  o.y = f2b(a[2]) | ((uint)f2b(a[3]) << 16);
  o.z = f2b(a[4]) | ((uint)f2b(a[5]) << 16);
  o.w = f2b(a[6]) | ((uint)f2b(a[7]) << 16);
  *(uint4*)(h + base) = o;
}

// ------ bf16 GEMM: O = leaky(A @ BT^T + bias), 128x256 tile, BK=32 ---------
// R13/R14 base. R15 FIX: with 64B LDS rows, bank base = (row&1)*16 + chunk*4,
// so the R11 key (rsel&3) left each 16-lane phase on only 4 of 8 bank-quads
// -> 4-way conflict on EVERY main-loop ds_read_b128 (measured 5.2M/dispatch,
// ~= unswizzled R1). New key (rsel>>1)&3: quad = (row&1)*4 + (g^key) covers
// all 8 quads exactly 2x per 16-lane phase (2-way = free, m136). Applied on
// BOTH sides (rule 21): stage key = (tid>>3)&3 (row = tid>>2; invariant for
// the B tile's +128-row second issue since bits 1-2 of row are preserved).
__global__ __launch_bounds__(512, 4) void gemm_bias_leaky(
    const ushort* __restrict__ A, const ushort* __restrict__ BT,
    const float* __restrict__ bias, ushort* __restrict__ Obf,
    float* __restrict__ Of32, const int* __restrict__ batch,
    uint* __restrict__ mvstage) {
  __shared__ alignas(16) ushort smem[36864];  // 72 KB
  ushort* const lA0 = smem;            // [128][32]  4096
  ushort* const lB0 = smem + 4096;     // [256][32]  8192
  ushort* const lA1 = smem + 12288;
  ushort* const lB1 = smem + 16384;
  ushort* const lA2 = smem + 24576;
  ushort* const lB2 = smem + 28672;

  const int tid = threadIdx.x;
  const int lane = tid & 63;
  const int wave = tid >> 6;
  const int wr = wave >> 2, wc = wave & 3;  // 2x4 waves; 64x64 out each

  // XCD swizzle (nwg = 2*512 = 1024, divisible by 8 -> bijective):
  const int lin = blockIdx.y * gridDim.x + blockIdx.x;
  const int nwg = gridDim.x * gridDim.y;
  const int wg = (lin & 7) * (nwg >> 3) + (lin >> 3);
  const int n0 = (wg & 1) * TBN;
  const size_t m0 = (size_t)(wg >> 1) * TBM;

  // staging: thread tid -> linear LDS 16B slot tid (A) / {tid, 512+tid} (B);
  // source row = slot>>2, source chunk = (slot&3) ^ ((row>>1)&3).
  const int srow = tid >> 2;                        // 0..127
  const int schunk = ((tid & 3) ^ ((tid >> 3) & 3)) * 8;  // swizzled global chunk

  f32x4 acc[4][4] = {};

  // fragment-read addressing
  const int rsel = lane & 15;
  const int g = lane >> 4;
  const int ch = (g ^ ((rsel >> 1) & 3)) * 8;  // swizzled chunk offset (ushorts)

#define STAGE(bufA, bufB, kt)                                                    \
  {                                                                              \
    const int k0_ = (kt) * TBK;                                                  \
    gload16(A + (m0 + srow) * D + k0_ + schunk, &(bufA)[tid * 8]);               \
    gload16(BT + (size_t)(n0 + srow) * D + k0_ + schunk, &(bufB)[tid * 8]);      \
    gload16(BT + (size_t)(n0 + 128 + srow) * D + k0_ + schunk,                   \
            &(bufB)[(512 + tid) * 8]);                                           \
  }

#define COMPUTE(bufA, bufB)                                                      \
  {                                                                              \
    __builtin_amdgcn_s_setprio(1);                                               \
    bf16x8 af_[4], bf_[4];                                                       \
    _Pragma("unroll") for (int j_ = 0; j_ < 4; ++j_)                             \
        bf_[j_] = *(const bf16x8*)&(bufB)[(wc * 64 + j_ * 16 + rsel) * TBK + ch];\
    _Pragma("unroll") for (int i_ = 0; i_ < 4; ++i_)                             \
        af_[i_] = *(const bf16x8*)&(bufA)[(wr * 64 + i_ * 16 + rsel) * TBK + ch];\
    _Pragma("unroll") for (int i_ = 0; i_ < 4; ++i_)                             \
        _Pragma("unroll") for (int j_ = 0; j_ < 4; ++j_)                         \
            acc[i_][j_] = __builtin_amdgcn_mfma_f32_16x16x32_bf16(               \
                af_[i_], bf_[j_], acc[i_][j_], 0, 0, 0);                         \
    __builtin_amdgcn_s_setprio(0);                                               \
  }

#define VMW(N)                                              \
  asm volatile("s_waitcnt vmcnt(" #N ")" ::: "memory");     \
  __builtin_amdgcn_sched_barrier(0)
#define BAR() __builtin_amdgcn_s_barrier()

  // K=512 -> 16 K-tiles; buffer b = tile%3; 2-tile-ahead, counted vmcnt.
  STAGE(lA0, lB0, 0); STAGE(lA1, lB1, 1); STAGE(lA2, lB2, 2);
  VMW(6); BAR(); COMPUTE(lA0, lB0); BAR(); STAGE(lA0, lB0, 3);   // t=0
  VMW(6); BAR(); COMPUTE(lA1, lB1); BAR(); STAGE(lA1, lB1, 4);   // t=1
  VMW(6); BAR(); COMPUTE(lA2, lB2); BAR(); STAGE(lA2, lB2, 5);   // t=2
  VMW(6); BAR(); COMPUTE(lA0, lB0); BAR(); STAGE(lA0, lB0, 6);   // t=3
  VMW(6); BAR(); COMPUTE(lA1, lB1); BAR(); STAGE(lA1, lB1, 7);   // t=4
  VMW(6); BAR(); COMPUTE(lA2, lB2); BAR(); STAGE(lA2, lB2, 8);   // t=5
  VMW(6); BAR(); COMPUTE(lA0, lB0); BAR(); STAGE(lA0, lB0, 9);   // t=6
  VMW(6); BAR(); COMPUTE(lA1, lB1); BAR(); STAGE(lA1, lB1, 10);  // t=7
  VMW(6); BAR(); COMPUTE(lA2, lB2); BAR(); STAGE(lA2, lB2, 11);  // t=8
  VMW(6); BAR(); COMPUTE(lA0, lB0); BAR(); STAGE(lA0, lB0, 12);  // t=9
  VMW(6); BAR(); COMPUTE(lA1, lB1); BAR(); STAGE(lA1, lB1, 13);  // t=10
  VMW(6); BAR(); COMPUTE(lA2, lB2); BAR(); STAGE(lA2, lB2, 14);  // t=11
  VMW(6); BAR(); COMPUTE(lA0, lB0); BAR(); STAGE(lA0, lB0, 15);  // t=12
  VMW(6); BAR(); COMPUTE(lA1, lB1); BAR();                       // t=13
  VMW(3); BAR(); COMPUTE(lA2, lB2); BAR();                       // t=14
  VMW(0); BAR(); COMPUTE(lA0, lB0);                              // t=15
#undef STAGE
#undef COMPUTE
#undef VMW

  __syncthreads();  // drain before epilogue reuses smem

  // ---- epilogue via two LDS half-tiles [64][CPAD] bf16 (33.8 KB) ----
  // C/D layout: col=lane&15, row=(lane>>4)*4+reg (m89-verified)
  const int rbase = g * 4;
#pragma unroll
  for (int h = 0; h < 2; ++h) {
    if (wr == h) {
#pragma unroll
      for (int j = 0; j < 4; ++j) {
        const int col = wc * 64 + j * 16 + rsel;
        const float bv = bias[n0 + col];
#pragma unroll
        for (int i = 0; i < 4; ++i) {
#pragma unroll
          for (int q = 0; q < 4; ++q) {
            const int lrow = i * 16 + rbase + q;  // 0..63
            float v = acc[i][j][q] + bv;
            v = (v > 0.f) ? v : 0.01f * v;
            smem[lrow * CPAD + col] = f2b(v);
          }
        }
      }
    }
    __syncthreads();
    // cooperative store: 64 rows x 512B contiguous
#pragma unroll
    for (int it = 0; it < 4; ++it) {
      const int slot = it * 512 + tid;  // 2048 slots
      const int row = slot >> 5;
      const int chunk = slot & 31;
      const uint4 vv = *(const uint4*)&smem[row * CPAD + chunk * 8];
      const size_t grow = m0 + h * 64 + row;
      if (Obf) *(uint4*)(Obf + grow * D + n0 + chunk * 8) = vv;
      if (Of32) {
        float4 f0, f1;
        f0.x = b_lo(vv.x); f0.y = b_hi(vv.x); f0.z = b_lo(vv.y); f0.w = b_hi(vv.y);
        f1.x = b_lo(vv.z); f1.y = b_hi(vv.z); f1.z = b_lo(vv.w); f1.w = b_hi(vv.w);
        float* op = Of32 + grow * D + n0 + chunk * 8;
        *(float4*)op = f0;
        *(float4*)(op + 4) = f1;
      }
    }
    // fused segment-max over this half-tile (still resident in LDS)
    if (mvstage) {
      const int col = tid & 255;          // 0..255 within n0 slice
      const int rh = tid >> 8;            // 0/1: rows rh*32..rh*32+31
      const size_t rowbase = m0 + h * 64 + rh * 32;
      float mx = -3.4e38f;
      int curg = batch[rowbase];
#pragma unroll 4
      for (int r = 0; r < 32; ++r) {
        const int gg = batch[rowbase + r];
        if (gg != curg) {
          atomicMax(&mvstage[(size_t)curg * D + n0 + col], encf(mx));
          mx = -3.4e38f;
          curg = gg;
        }
        mx = fmaxf(mx, b_lo((uint)smem[(rh * 32 + r) * CPAD + col]));
      }
      atomicMax(&mvstage[(size_t)curg * D + n0 + col], encf(mx));
    }
    __syncthreads();
  }
}

// ------------- pool projection, split-K (R10-verified); mv is ENCODED ------
__global__ __launch_bounds__(256) void pool_partial(
    const uint* __restrict__ mv, const float* __restrict__ proj_w,
    const float* __restrict__ pool_w, float* __restrict__ pp) {
  const int g = blockIdx.x;                      // 64
  const int o = blockIdx.y * 256 + threadIdx.x;  // 2 x 256
  const int s = blockIdx.z >> 2, kq = blockIdx.z & 3;
  const float* W = (s == 0) ? proj_w : pool_w + (size_t)(s - 1) * D * D;
  const uint* m = mv + ((size_t)s * 64 + g) * D + kq * 128;
  const float* Wp = W + (size_t)(kq * 128) * D + o;
  float acc = 0.f;
#pragma unroll 8
  for (int k = 0; k < 128; ++k) acc = fmaf(decf(m[k]), Wp[(size_t)k * D], acc);
  pp[((size_t)blockIdx.z * 64 + g) * D + o] = acc;
}

__global__ __launch_bounds__(256) void pool_reduce(
    const float* __restrict__ pp, const float* __restrict__ proj_b,
    const float* __restrict__ pool_b, float* __restrict__ part) {
  const int i = blockIdx.x * 256 + threadIdx.x;  // < 64*512
  const int g = i >> 9, o = i & (D - 1);
  float acc = proj_b[o] + pool_b[o] + pool_b[D + o] + pool_b[2 * D + o];
#pragma unroll
  for (int s = 0; s < 16; ++s) acc += pp[((size_t)s * 64 + g) * D + o];
  part[i] = acc;
}

// ---------------------------------------------------------------------------
extern "C" void kernel_launch(void* const* d_in, const int* in_sizes, int n_in,
                              void* d_out, int out_size, void* d_ws, size_t ws_size,
                              hipStream_t stream) {
  const float* x = (const float*)d_in[0];
  const int* ei = (const int*)d_in[1];
  const int* batch = (const int*)d_in[2];
  const float* proj_w = (const float*)d_in[3];
  const float* proj_b = (const float*)d_in[4];
  const float* lin1_w = (const float*)d_in[5];
  const float* lin1_b = (const float*)d_in[6];
  const float* lin2_w = (const float*)d_in[7];
  const float* lin2_b = (const float*)d_in[8];
  const float* eps = (const float*)d_in[9];
  const float* pool_w = (const float*)d_in[10];
  const float* pool_b = (const float*)d_in[11];

  const int N = in_sizes[0] / D;  // 65536
  const int E = in_sizes[1] / 2;  // 524288
  const int B = 64;
  const int* src = ei;
  const int* dst = ei + E;

  float* part = (float*)d_out;         // [64][512]
  float* xout = part + (size_t)B * D;  // [N][512]

  // workspace carve (~212 MB)
  char* w = (char*)d_ws;
  ushort* xb = (ushort*)w;   w += (size_t)N * D * 2;
  ushort* hb = (ushort*)w;   w += (size_t)N * D * 2;
  ushort* tb = (ushort*)w;   w += (size_t)N * D * 2;
  ushort* l1bt = (ushort*)w; w += (size_t)3 * D * D * 2;
  ushort* l2bt = (ushort*)w; w += (size_t)3 * D * D * 2;
  int* rowptr = (int*)w;     w += (size_t)(N + 4) * 4;
  int* cursor = (int*)w;     w += (size_t)N * 4;
  int* deg = (int*)w;        w += (size_t)N * 4;
  int* csr = (int*)w;        w += (size_t)E * 4;
  int* bsum = (int*)w;       w += 256 * 4;
  int* gstart = (int*)w;     w += 128 * 4;
  uint* mvall = (uint*)w;     w += (size_t)4 * B * D * 4;   // [4][64][512] encoded
  float* pp = (float*)w;      w += (size_t)16 * B * D * 4;  // [16][64][512]
  (void)ws_size; (void)n_in; (void)out_size; (void)gstart;

  (void)hipMemsetAsync(deg, 0, (size_t)N * 4, stream);
  (void)hipMemsetAsync(mvall, 0, (size_t)4 * B * D * 4, stream);
  // convert + fused stage-0 segmax
  f32_to_bf16_segmax<<<N / 128, 256, 0, stream>>>(x, xb, batch, mvall);
  transpose_all<<<dim3(8, 8, 6), 256, 0, stream>>>(lin1_w, lin2_w, l1bt, l2bt);
  count_deg<<<(E + 255) / 256, 256, 0, stream>>>(dst, deg, E);
  scan_block<<<N / 256, 256, 0, stream>>>(deg, rowptr, bsum);
  scan_block<<<1, 256, 0, stream>>>(bsum, bsum, (int*)nullptr);
  scan_fixup<<<N / 256, 256, 0, stream>>>(rowptr, bsum, cursor, N, E);
  fill_csr<<<(E + 255) / 256, 256, 0, stream>>>(src, dst, cursor, csr, E);

  for (int l = 0; l < 3; ++l) {
    agg_kernel<<<N / 4, 256, 0, stream>>>(xb, rowptr, csr, eps, l, hb);
    gemm_bias_leaky<<<dim3(D / TBN, N / TBM), 512, 0, stream>>>(
        hb, l1bt + (size_t)l * D * D, lin1_b + (size_t)l * D, tb, nullptr,
        batch, nullptr);
    gemm_bias_leaky<<<dim3(D / TBN, N / TBM), 512, 0, stream>>>(
        tb, l2bt + (size_t)l * D * D, lin2_b + (size_t)l * D,
        (l == 2) ? nullptr : xb,            // last layer: xb is dead, skip 67MB write
        (l == 2) ? xout : nullptr, batch,
        mvall + (size_t)(l + 1) * B * D);   // fused segmax stage l+1
  }

  // split-K pool projection (decodes mvall)
  pool_partial<<<dim3(B, 2, 16), 256, 0, stream>>>(mvall, proj_w, pool_w, pp);
  pool_reduce<<<B * D / 256, 256, 0, stream>>>(pp, proj_b, pool_b, part);
}